// Round 2
// baseline (992.506 us; speedup 1.0000x reference)
//
#include <hip/hip_runtime.h>
#include <hip/hip_fp16.h>

typedef _Float16 half8 __attribute__((ext_vector_type(8)));
typedef float f32x4 __attribute__((ext_vector_type(4)));

#define HID 128
#define NDIM 16
#define NCONV 8

static __device__ __forceinline__ half8 load_h8(const _Float16* p) {
    return *(const half8*)p;
}

// ---------------- weight prep: f16 transposed weights ----------------
// WABT[l] : [256][128] f16. rows j<128:  W1A_T[j][k] = W1[l][k][j] - W1[l][128+k][j]
//                           rows 128+j:  W1B_T[j][k] = W1[l][128+k][j]
// W2T[l]  : [128][128] f16. W2T[j][k] = W2[l][k][j]
__global__ void prep_weights(const float* __restrict__ W1, const float* __restrict__ W2,
                             _Float16* __restrict__ WABT, _Float16* __restrict__ W2T) {
    int idx = blockIdx.x * blockDim.x + threadIdx.x;
    int total = NCONV * HID * HID;
    if (idx >= total) return;
    int l = idx / (HID * HID);
    int r = idx % (HID * HID);
    int j = r / HID;
    int k = r % HID;
    const float* w1 = W1 + (size_t)l * 2 * HID * HID;
    float top = w1[k * HID + j];
    float bot = w1[(HID + k) * HID + j];
    _Float16* wab = WABT + (size_t)l * 2 * HID * HID;
    wab[j * HID + k] = (_Float16)(top - bot);
    wab[(HID + j) * HID + k] = (_Float16)bot;
    const float* w2 = W2 + (size_t)l * HID * HID;
    W2T[(size_t)l * HID * HID + j * HID + k] = (_Float16)w2[k * HID + j];
}

// enc_fc weight transpose -> f16: encT[j][k] = eW[k][j]
__global__ void prep_enc(const float* __restrict__ eW, _Float16* __restrict__ encT) {
    int idx = blockIdx.x * blockDim.x + threadIdx.x;
    if (idx >= HID * HID) return;
    int j = idx / HID;
    int k = idx % HID;
    encT[j * HID + k] = (_Float16)eW[k * HID + j];
}

// ---------------- time embedding ----------------
__global__ void time_emb_kernel(const float* __restrict__ t, const float* __restrict__ tpW,
                                const float* __restrict__ tpb, float* __restrict__ temb) {
    __shared__ float sc[64];
    int i = threadIdx.x;
    float tv = t[0];
    if (i < 32) {
        float f = expf(-4.0f + 8.0f * (float)i / 31.0f);
        sc[i] = sinf(tv * f);
        sc[32 + i] = cosf(tv * f);
    }
    __syncthreads();
    if (i < 16) {
        float acc = tpb[i];
        for (int k = 0; k < 64; k++) acc += sc[k] * tpW[k * NDIM + i];
        temb[i] = acc;
    }
}

// ---------------- node embedding: h = (x + temb) @ neW + neb -> f16 ----------------
__global__ void node_emb_kernel(const float* __restrict__ x, const float* __restrict__ temb,
                                const float* __restrict__ W, const float* __restrict__ b,
                                _Float16* __restrict__ h16, int n) {
    __shared__ float sx[NDIM];
    int node = blockIdx.x;
    if (node >= n) return;
    int j = threadIdx.x;
    if (j < NDIM) sx[j] = x[(size_t)node * NDIM + j] + temb[j];
    __syncthreads();
    float acc = b[j];
    #pragma unroll
    for (int d = 0; d < NDIM; d++) acc += sx[d] * W[d * HID + j];
    h16[(size_t)node * HID + j] = (_Float16)acc;
}

// ---------------- CSR build ----------------
__global__ void count_deg(const int* __restrict__ ei, int* __restrict__ deg, int E) {
    int e = blockIdx.x * blockDim.x + threadIdx.x;
    if (e < E) atomicAdd(&deg[ei[E + e]], 1);   // dst row
}

__global__ void scan_csr(const int* __restrict__ deg, int* __restrict__ rowptr,
                         int* __restrict__ cursor, int n) {
    __shared__ int part[1024];
    int t = threadIdx.x;
    int chunk = (n + 1023) / 1024;
    int base = t * chunk;
    int s = 0;
    for (int i = 0; i < chunk; i++) {
        int id = base + i;
        if (id < n) s += deg[id];
    }
    part[t] = s;
    __syncthreads();
    for (int off = 1; off < 1024; off <<= 1) {
        int v = 0;
        if (t >= off) v = part[t - off];
        __syncthreads();
        part[t] += v;
        __syncthreads();
    }
    int pre = (t == 0) ? 0 : part[t - 1];
    for (int i = 0; i < chunk; i++) {
        int id = base + i;
        if (id < n) {
            rowptr[id] = pre;
            cursor[id] = pre;
            pre += deg[id];
        }
    }
    if (t == 1023) rowptr[n] = part[1023];
}

__global__ void fill_csr(const int* __restrict__ ei, int* __restrict__ cursor,
                         int* __restrict__ elist, int E) {
    int e = blockIdx.x * blockDim.x + threadIdx.x;
    if (e < E) {
        int d = ei[E + e];
        int pos = atomicAdd(&cursor[d], 1);
        elist[pos] = ei[e];   // src
    }
}

// ---------------- generic node GEMM: Y[n][OUT] = A[n][128] @ WT^T + bias ----------------
// WT is [OUT][128] f16 (row j = output column j). bias applied for col<128, else 0.
// Each wave: one 16-row m-tile x two 16-col j-tiles (8 MFMAs).
template<int OUT>
__global__ __launch_bounds__(256) void gemm_h(const _Float16* __restrict__ A,
                                              const _Float16* __restrict__ WT,
                                              const float* __restrict__ bias,
                                              _Float16* __restrict__ Y, int n) {
    constexpr int JW = OUT / 32;    // j-pairs per m-tile
    int gw = (blockIdx.x * blockDim.x + threadIdx.x) >> 6;
    int lane = threadIdx.x & 63;
    int nmt = (n + 15) >> 4;
    if (gw >= nmt * JW) return;
    int mt = gw / JW;
    int jp = gw % JW;
    int c = lane & 15;
    int kq = lane >> 4;

    int arow = mt * 16 + c;
    half8 a[4];
    #pragma unroll
    for (int kb = 0; kb < 4; kb++) {
        if (arow < n) a[kb] = load_h8(A + (size_t)arow * HID + kb * 32 + kq * 8);
        else          a[kb] = (half8)(_Float16)0;
    }

    f32x4 acc[2];
    #pragma unroll
    for (int p = 0; p < 2; p++) {
        acc[p][0] = 0.f; acc[p][1] = 0.f; acc[p][2] = 0.f; acc[p][3] = 0.f;
        int wrow = (jp * 2 + p) * 16 + c;
        #pragma unroll
        for (int kb = 0; kb < 4; kb++) {
            half8 b = load_h8(WT + (size_t)wrow * HID + kb * 32 + kq * 8);
            acc[p] = __builtin_amdgcn_mfma_f32_16x16x32_f16(a[kb], b, acc[p], 0, 0, 0);
        }
    }

    #pragma unroll
    for (int p = 0; p < 2; p++) {
        int col = (jp * 2 + p) * 16 + c;
        float bv = (col < HID) ? bias[col] : 0.f;
        #pragma unroll
        for (int r = 0; r < 4; r++) {
            int row = mt * 16 + kq * 4 + r;
            if (row < n) Y[(size_t)row * OUT + col] = (_Float16)(acc[p][r] + bv);
        }
    }
}

// ---------------- EdgeConv: out[v][j] = max_e relu(A[v]+B[src_e]) @ W2 + b2 ----------------
// One node per wave. W2 staged in LDS with XOR swizzle (stride-256B rows -> 2-way max).
__global__ __launch_bounds__(256, 4) void edge_conv(const _Float16* __restrict__ AB,
                                                    const _Float16* __restrict__ W2T_l,
                                                    const float* __restrict__ b2_l,
                                                    const int* __restrict__ rowptr,
                                                    const int* __restrict__ elist,
                                                    _Float16* __restrict__ hout, int n) {
    __shared__ char w2s[HID * 256];     // 32 KB, swizzled
    __shared__ float b2s[HID];
    int tid = threadIdx.x;
    {
        int row = tid >> 1;             // 0..127
        int half = tid & 1;
        const _Float16* srcp = W2T_l + (size_t)row * HID + half * 64;
        #pragma unroll
        for (int j = 0; j < 8; j++) {
            int colb = half * 128 + j * 16;
            half8 v = load_h8(srcp + j * 8);
            *(half8*)(w2s + row * 256 + (colb ^ ((row & 7) << 4))) = v;
        }
        if (tid < HID) b2s[tid] = b2_l[tid];
    }
    __syncthreads();

    int lane = tid & 63;
    int c = lane & 15;
    int kq = lane >> 4;
    int gw = (blockIdx.x * blockDim.x + tid) >> 6;
    int nw = (gridDim.x * blockDim.x) >> 6;

    for (int v = gw; v < n; v += nw) {
        int rbeg = rowptr[v];
        int deg = rowptr[v + 1] - rbeg;     // real in-edges; +1 implicit self-loop
        int ntile = (deg + 16) >> 4;        // ceil((deg+1)/16)

        half8 af[4];
        #pragma unroll
        for (int kb = 0; kb < 4; kb++)
            af[kb] = load_h8(AB + (size_t)v * 256 + kb * 32 + kq * 8);

        f32x4 macc[8];
        #pragma unroll
        for (int cb = 0; cb < 8; cb++) {
            macc[cb][0] = -3.0e38f; macc[cb][1] = -3.0e38f;
            macc[cb][2] = -3.0e38f; macc[cb][3] = -3.0e38f;
        }

        for (int tI = 0; tI < ntile; tI++) {
            int gidx = tI * 16 + c;
            int src = (gidx < deg) ? elist[rbeg + gidx] : v;   // pad with self-loop

            half8 hf[4];
            #pragma unroll
            for (int kb = 0; kb < 4; kb++) {
                half8 s = af[kb] + load_h8(AB + (size_t)src * 256 + 128 + kb * 32 + kq * 8);
                #pragma unroll
                for (int e = 0; e < 8; e++) s[e] = (s[e] > (_Float16)0) ? s[e] : (_Float16)0;
                hf[kb] = s;
            }
            #pragma unroll
            for (int cb = 0; cb < 8; cb++) {
                f32x4 d = {0.f, 0.f, 0.f, 0.f};
                int row = cb * 16 + c;
                #pragma unroll
                for (int kb = 0; kb < 4; kb++) {
                    int colb = kb * 64 + kq * 16;
                    half8 w = *(const half8*)(w2s + row * 256 + (colb ^ ((row & 7) << 4)));
                    d = __builtin_amdgcn_mfma_f32_16x16x32_f16(hf[kb], w, d, 0, 0, 0);
                }
                #pragma unroll
                for (int r = 0; r < 4; r++) macc[cb][r] = fmaxf(macc[cb][r], d[r]);
            }
        }

        #pragma unroll
        for (int cb = 0; cb < 8; cb++) {
            float m = fmaxf(fmaxf(macc[cb][0], macc[cb][1]), fmaxf(macc[cb][2], macc[cb][3]));
            m = fmaxf(m, __shfl_xor(m, 16));
            m = fmaxf(m, __shfl_xor(m, 32));
            m += b2s[cb * 16 + c];
            if (lane < 16) hout[(size_t)v * HID + cb * 16 + c] = (_Float16)m;
        }
    }
}

// ---------------- decoder FC: out = h @ dW + db  (fp32 out [N][16]) ----------------
__global__ void fc_dec(const _Float16* __restrict__ h16, const float* __restrict__ W,
                       const float* __restrict__ b, float* __restrict__ out, int n) {
    __shared__ float row[HID];
    __shared__ float part[64];
    int node = blockIdx.x;
    if (node >= n) return;
    int t = threadIdx.x;
    row[t] = (float)h16[(size_t)node * HID + t];
    row[64 + t] = (float)h16[(size_t)node * HID + 64 + t];
    __syncthreads();
    int j = t & 15;
    int ks = t >> 4;   // 0..3, each covers 32 k
    float p = 0.f;
    for (int k = ks * 32; k < ks * 32 + 32; k++) p += row[k] * W[k * NDIM + j];
    part[t] = p;
    __syncthreads();
    if (t < 16) {
        float o = b[j] + part[j] + part[16 + j] + part[32 + j] + part[48 + j];
        out[(size_t)node * NDIM + j] = o;
    }
}

// ---------------- host ----------------
extern "C" void kernel_launch(void* const* d_in, const int* in_sizes, int n_in,
                              void* d_out, int out_size, void* d_ws, size_t ws_size,
                              hipStream_t stream) {
    const float* x   = (const float*)d_in[0];
    const int*   ei  = (const int*)d_in[1];
    const float* t   = (const float*)d_in[2];
    const float* neW = (const float*)d_in[3];
    const float* neb = (const float*)d_in[4];
    const float* cW1 = (const float*)d_in[5];
    const float* cb1 = (const float*)d_in[6];
    const float* cW2 = (const float*)d_in[7];
    const float* cb2 = (const float*)d_in[8];
    const float* eW  = (const float*)d_in[9];
    const float* eb  = (const float*)d_in[10];
    const float* dW  = (const float*)d_in[11];
    const float* db  = (const float*)d_in[12];
    const float* tpW = (const float*)d_in[13];
    const float* tpb = (const float*)d_in[14];

    int N = in_sizes[0] / NDIM;
    int E = in_sizes[1] / 2;

    char* w = (char*)d_ws;
    auto alloc = [&](size_t bytes) {
        void* p = (void*)w;
        w += (bytes + 255) & ~(size_t)255;
        return p;
    };
    float*     temb   = (float*)alloc(64 * 4);
    _Float16*  hA     = (_Float16*)alloc((size_t)N * HID * 2);
    _Float16*  hB     = (_Float16*)alloc((size_t)N * HID * 2);
    _Float16*  AB     = (_Float16*)alloc((size_t)N * 2 * HID * 2);
    _Float16*  WABT   = (_Float16*)alloc((size_t)NCONV * 2 * HID * HID * 2);
    _Float16*  W2T    = (_Float16*)alloc((size_t)NCONV * HID * HID * 2);
    _Float16*  encT   = (_Float16*)alloc((size_t)HID * HID * 2);
    int*       deg    = (int*)alloc((size_t)N * 4);
    int*       rowptr = (int*)alloc((size_t)(N + 1) * 4);
    int*       cursor = (int*)alloc((size_t)N * 4);
    int*       elist  = (int*)alloc((size_t)E * 4);

    // weights + time embedding + node embedding
    prep_weights<<<(NCONV * HID * HID + 255) / 256, 256, 0, stream>>>(cW1, cW2, WABT, W2T);
    prep_enc<<<(HID * HID + 255) / 256, 256, 0, stream>>>(eW, encT);
    time_emb_kernel<<<1, 64, 0, stream>>>(t, tpW, tpb, temb);
    node_emb_kernel<<<N, HID, 0, stream>>>(x, temb, neW, neb, hA, N);

    // CSR by dst
    hipMemsetAsync(deg, 0, (size_t)N * 4, stream);
    count_deg<<<(E + 255) / 256, 256, 0, stream>>>(ei, deg, E);
    scan_csr<<<1, 1024, 0, stream>>>(deg, rowptr, cursor, N);
    fill_csr<<<(E + 255) / 256, 256, 0, stream>>>(ei, cursor, elist, E);

    int nmt = (N + 15) / 16;
    int ab_blocks = (nmt * 8 + 3) / 4;      // OUT=256 -> JW=8
    int fc_blocks = (nmt * 4 + 3) / 4;      // OUT=128 -> JW=4
    int ec_blocks = (N + 3) / 4;            // one node per wave

    _Float16* cur = hA;
    for (int l = 0; l < NCONV; l++) {
        if (l == 4) {
            gemm_h<128><<<fc_blocks, 256, 0, stream>>>(cur, encT, eb, hB, N);
            cur = hB;
        }
        gemm_h<256><<<ab_blocks, 256, 0, stream>>>(cur, WABT + (size_t)l * 2 * HID * HID,
                                                   cb1 + (size_t)l * HID, AB, N);
        edge_conv<<<ec_blocks, 256, 0, stream>>>(AB, W2T + (size_t)l * HID * HID,
                                                 cb2 + (size_t)l * HID, rowptr, elist, cur, N);
    }

    fc_dec<<<N, HID, 0, stream>>>(cur, dW, db, (float*)d_out, N);
}

// Round 3
// 953.337 us; speedup vs baseline: 1.0411x; 1.0411x over previous
//
#include <hip/hip_runtime.h>
#include <hip/hip_fp16.h>

typedef _Float16 half8 __attribute__((ext_vector_type(8)));
typedef float f32x4 __attribute__((ext_vector_type(4)));

#define HID 128
#define NDIM 16
#define NCONV 8

static __device__ __forceinline__ half8 load_h8(const _Float16* p) {
    return *(const half8*)p;
}

// ---------------- weight prep: f16 transposed weights ----------------
// WABT[l] : [256][128] f16. rows j<128:  W1A_T[j][k] = W1[l][k][j] - W1[l][128+k][j]
//                           rows 128+j:  W1B_T[j][k] = W1[l][128+k][j]
// W2T[l]  : [128][128] f16. W2T[j][k] = W2[l][k][j]
__global__ void prep_weights(const float* __restrict__ W1, const float* __restrict__ W2,
                             _Float16* __restrict__ WABT, _Float16* __restrict__ W2T) {
    int idx = blockIdx.x * blockDim.x + threadIdx.x;
    int total = NCONV * HID * HID;
    if (idx >= total) return;
    int l = idx / (HID * HID);
    int r = idx % (HID * HID);
    int j = r / HID;
    int k = r % HID;
    const float* w1 = W1 + (size_t)l * 2 * HID * HID;
    float top = w1[k * HID + j];
    float bot = w1[(HID + k) * HID + j];
    _Float16* wab = WABT + (size_t)l * 2 * HID * HID;
    wab[j * HID + k] = (_Float16)(top - bot);
    wab[(HID + j) * HID + k] = (_Float16)bot;
    const float* w2 = W2 + (size_t)l * HID * HID;
    W2T[(size_t)l * HID * HID + j * HID + k] = (_Float16)w2[k * HID + j];
}

// enc_fc weight transpose -> f16: encT[j][k] = eW[k][j]
__global__ void prep_enc(const float* __restrict__ eW, _Float16* __restrict__ encT) {
    int idx = blockIdx.x * blockDim.x + threadIdx.x;
    if (idx >= HID * HID) return;
    int j = idx / HID;
    int k = idx % HID;
    encT[j * HID + k] = (_Float16)eW[k * HID + j];
}

// ---------------- time embedding ----------------
__global__ void time_emb_kernel(const float* __restrict__ t, const float* __restrict__ tpW,
                                const float* __restrict__ tpb, float* __restrict__ temb) {
    __shared__ float sc[64];
    int i = threadIdx.x;
    float tv = t[0];
    if (i < 32) {
        float f = expf(-4.0f + 8.0f * (float)i / 31.0f);
        sc[i] = sinf(tv * f);
        sc[32 + i] = cosf(tv * f);
    }
    __syncthreads();
    if (i < 16) {
        float acc = tpb[i];
        for (int k = 0; k < 64; k++) acc += sc[k] * tpW[k * NDIM + i];
        temb[i] = acc;
    }
}

// ---------------- node embedding: h = (x + temb) @ neW + neb -> f16 ----------------
__global__ void node_emb_kernel(const float* __restrict__ x, const float* __restrict__ temb,
                                const float* __restrict__ W, const float* __restrict__ b,
                                _Float16* __restrict__ h16, int n) {
    __shared__ float sx[NDIM];
    int node = blockIdx.x;
    if (node >= n) return;
    int j = threadIdx.x;
    if (j < NDIM) sx[j] = x[(size_t)node * NDIM + j] + temb[j];
    __syncthreads();
    float acc = b[j];
    #pragma unroll
    for (int d = 0; d < NDIM; d++) acc += sx[d] * W[d * HID + j];
    h16[(size_t)node * HID + j] = (_Float16)acc;
}

// ---------------- CSR build ----------------
__global__ void count_deg(const int* __restrict__ ei, int* __restrict__ deg, int E) {
    int e = blockIdx.x * blockDim.x + threadIdx.x;
    if (e < E) atomicAdd(&deg[ei[E + e]], 1);   // dst row
}

__global__ void scan_csr(const int* __restrict__ deg, int* __restrict__ rowptr,
                         int* __restrict__ cursor, int n) {
    __shared__ int part[1024];
    int t = threadIdx.x;
    int chunk = (n + 1023) / 1024;
    int base = t * chunk;
    int s = 0;
    for (int i = 0; i < chunk; i++) {
        int id = base + i;
        if (id < n) s += deg[id];
    }
    part[t] = s;
    __syncthreads();
    for (int off = 1; off < 1024; off <<= 1) {
        int v = 0;
        if (t >= off) v = part[t - off];
        __syncthreads();
        part[t] += v;
        __syncthreads();
    }
    int pre = (t == 0) ? 0 : part[t - 1];
    for (int i = 0; i < chunk; i++) {
        int id = base + i;
        if (id < n) {
            rowptr[id] = pre;
            cursor[id] = pre;
            pre += deg[id];
        }
    }
    if (t == 1023) rowptr[n] = part[1023];
}

__global__ void fill_csr(const int* __restrict__ ei, int* __restrict__ cursor,
                         int* __restrict__ elist, int E) {
    int e = blockIdx.x * blockDim.x + threadIdx.x;
    if (e < E) {
        int d = ei[E + e];
        int pos = atomicAdd(&cursor[d], 1);
        elist[pos] = ei[e];   // src
    }
}

// ---------------- generic node GEMM: Y[n][OUT] = A[n][128] @ WT^T + bias ----------------
template<int OUT>
__global__ __launch_bounds__(256) void gemm_h(const _Float16* __restrict__ A,
                                              const _Float16* __restrict__ WT,
                                              const float* __restrict__ bias,
                                              _Float16* __restrict__ Y, int n) {
    constexpr int JW = OUT / 32;    // j-pairs per m-tile
    int gw = (blockIdx.x * blockDim.x + threadIdx.x) >> 6;
    int lane = threadIdx.x & 63;
    int nmt = (n + 15) >> 4;
    if (gw >= nmt * JW) return;
    int mt = gw / JW;
    int jp = gw % JW;
    int c = lane & 15;
    int kq = lane >> 4;

    int arow = mt * 16 + c;
    half8 a[4];
    #pragma unroll
    for (int kb = 0; kb < 4; kb++) {
        if (arow < n) a[kb] = load_h8(A + (size_t)arow * HID + kb * 32 + kq * 8);
        else          a[kb] = (half8)(_Float16)0;
    }

    f32x4 acc[2];
    #pragma unroll
    for (int p = 0; p < 2; p++) {
        acc[p][0] = 0.f; acc[p][1] = 0.f; acc[p][2] = 0.f; acc[p][3] = 0.f;
        int wrow = (jp * 2 + p) * 16 + c;
        #pragma unroll
        for (int kb = 0; kb < 4; kb++) {
            half8 b = load_h8(WT + (size_t)wrow * HID + kb * 32 + kq * 8);
            acc[p] = __builtin_amdgcn_mfma_f32_16x16x32_f16(a[kb], b, acc[p], 0, 0, 0);
        }
    }

    #pragma unroll
    for (int p = 0; p < 2; p++) {
        int col = (jp * 2 + p) * 16 + c;
        float bv = (col < HID) ? bias[col] : 0.f;
        #pragma unroll
        for (int r = 0; r < 4; r++) {
            int row = mt * 16 + kq * 4 + r;
            if (row < n) Y[(size_t)row * OUT + col] = (_Float16)(acc[p][r] + bv);
        }
    }
}

// ---------------- EdgeConv: out[v][j] = max_e relu(A[v]+B[src_e]) @ W2 + b2 ----------------
// One node per wave. W2 in LDS, FRAGMENT-MAJOR layout: frag(kb,cb,lane) at
// ((kb*8+cb)*64+lane)*16B -> every ds_read_b128 is lane-consecutive (0 conflicts).
// Scalar running max (macc[8]) keeps VGPR need ~60 + 32 acc -> fits 4 waves/SIMD.
__global__ __launch_bounds__(256, 4) void edge_conv(const _Float16* __restrict__ AB,
                                                    const _Float16* __restrict__ W2T_l,
                                                    const float* __restrict__ b2_l,
                                                    const int* __restrict__ rowptr,
                                                    const int* __restrict__ elist,
                                                    _Float16* __restrict__ hout, int n) {
    __shared__ _Float16 w2s[2048 * 8];   // 2048 frags x 16B = 32 KB
    __shared__ float b2s[HID];
    int tid = threadIdx.x;
    #pragma unroll
    for (int i = 0; i < 8; i++) {
        int fid = i * 256 + tid;
        int c = fid & 15;
        int kq = (fid >> 4) & 3;
        int grp = fid >> 6;          // kb*8+cb
        int kb = grp >> 3;
        int cb = grp & 7;
        half8 v = load_h8(W2T_l + (size_t)(cb * 16 + c) * HID + kb * 32 + kq * 8);
        *(half8*)(w2s + (size_t)fid * 8) = v;
    }
    if (tid < HID) b2s[tid] = b2_l[tid];
    __syncthreads();

    int lane = tid & 63;
    int c = lane & 15;
    int kq = lane >> 4;
    int gw = (blockIdx.x * blockDim.x + tid) >> 6;
    int nw = (gridDim.x * blockDim.x) >> 6;

    for (int v = gw; v < n; v += nw) {
        int rbeg = rowptr[v];
        int deg = rowptr[v + 1] - rbeg;     // real in-edges; +1 implicit self-loop
        int ntile = (deg + 16) >> 4;        // ceil((deg+1)/16)

        half8 af[4];
        #pragma unroll
        for (int kb = 0; kb < 4; kb++)
            af[kb] = load_h8(AB + (size_t)v * 256 + kb * 32 + kq * 8);

        float macc[8];
        #pragma unroll
        for (int cb = 0; cb < 8; cb++) macc[cb] = -3.0e38f;

        for (int tI = 0; tI < ntile; tI++) {
            int gidx = tI * 16 + c;
            int src = (gidx < deg) ? elist[rbeg + gidx] : v;   // pad with self-loop

            // prefetch the 4 B fragments of this edge's row
            const _Float16* bp = AB + (size_t)src * 256 + 128 + kq * 8;
            half8 bs[4];
            #pragma unroll
            for (int kb = 0; kb < 4; kb++) bs[kb] = load_h8(bp + kb * 32);

            f32x4 d[8];
            #pragma unroll
            for (int cb = 0; cb < 8; cb++) { d[cb][0] = 0.f; d[cb][1] = 0.f; d[cb][2] = 0.f; d[cb][3] = 0.f; }

            #pragma unroll
            for (int kb = 0; kb < 4; kb++) {
                half8 s = af[kb] + bs[kb];
                #pragma unroll
                for (int e = 0; e < 8; e++) s[e] = (s[e] > (_Float16)0) ? s[e] : (_Float16)0;
                #pragma unroll
                for (int cb = 0; cb < 8; cb++) {
                    half8 w = *(const half8*)(w2s + ((size_t)((kb * 8 + cb) * 64 + lane)) * 8);
                    d[cb] = __builtin_amdgcn_mfma_f32_16x16x32_f16(s, w, d[cb], 0, 0, 0);
                }
            }
            #pragma unroll
            for (int cb = 0; cb < 8; cb++) {
                float m0 = fmaxf(fmaxf(d[cb][0], d[cb][1]), fmaxf(d[cb][2], d[cb][3]));
                macc[cb] = fmaxf(macc[cb], m0);
            }
        }

        #pragma unroll
        for (int cb = 0; cb < 8; cb++) {
            float m = macc[cb];
            m = fmaxf(m, __shfl_xor(m, 16));
            m = fmaxf(m, __shfl_xor(m, 32));
            m += b2s[cb * 16 + c];
            if (lane < 16) hout[(size_t)v * HID + cb * 16 + c] = (_Float16)m;
        }
    }
}

// ---------------- decoder FC: out = h @ dW + db  (fp32 out [N][16]) ----------------
__global__ void fc_dec(const _Float16* __restrict__ h16, const float* __restrict__ W,
                       const float* __restrict__ b, float* __restrict__ out, int n) {
    __shared__ float row[HID];
    __shared__ float part[64];
    int node = blockIdx.x;
    if (node >= n) return;
    int t = threadIdx.x;
    row[t] = (float)h16[(size_t)node * HID + t];
    row[64 + t] = (float)h16[(size_t)node * HID + 64 + t];
    __syncthreads();
    int j = t & 15;
    int ks = t >> 4;   // 0..3, each covers 32 k
    float p = 0.f;
    for (int k = ks * 32; k < ks * 32 + 32; k++) p += row[k] * W[k * NDIM + j];
    part[t] = p;
    __syncthreads();
    if (t < 16) {
        float o = b[j] + part[j] + part[16 + j] + part[32 + j] + part[48 + j];
        out[(size_t)node * NDIM + j] = o;
    }
}

// ---------------- host ----------------
extern "C" void kernel_launch(void* const* d_in, const int* in_sizes, int n_in,
                              void* d_out, int out_size, void* d_ws, size_t ws_size,
                              hipStream_t stream) {
    const float* x   = (const float*)d_in[0];
    const int*   ei  = (const int*)d_in[1];
    const float* t   = (const float*)d_in[2];
    const float* neW = (const float*)d_in[3];
    const float* neb = (const float*)d_in[4];
    const float* cW1 = (const float*)d_in[5];
    const float* cb1 = (const float*)d_in[6];
    const float* cW2 = (const float*)d_in[7];
    const float* cb2 = (const float*)d_in[8];
    const float* eW  = (const float*)d_in[9];
    const float* eb  = (const float*)d_in[10];
    const float* dW  = (const float*)d_in[11];
    const float* db  = (const float*)d_in[12];
    const float* tpW = (const float*)d_in[13];
    const float* tpb = (const float*)d_in[14];

    int N = in_sizes[0] / NDIM;
    int E = in_sizes[1] / 2;

    char* w = (char*)d_ws;
    auto alloc = [&](size_t bytes) {
        void* p = (void*)w;
        w += (bytes + 255) & ~(size_t)255;
        return p;
    };
    float*     temb   = (float*)alloc(64 * 4);
    _Float16*  hA     = (_Float16*)alloc((size_t)N * HID * 2);
    _Float16*  hB     = (_Float16*)alloc((size_t)N * HID * 2);
    _Float16*  AB     = (_Float16*)alloc((size_t)N * 2 * HID * 2);
    _Float16*  WABT   = (_Float16*)alloc((size_t)NCONV * 2 * HID * HID * 2);
    _Float16*  W2T    = (_Float16*)alloc((size_t)NCONV * HID * HID * 2);
    _Float16*  encT   = (_Float16*)alloc((size_t)HID * HID * 2);
    int*       deg    = (int*)alloc((size_t)N * 4);
    int*       rowptr = (int*)alloc((size_t)(N + 1) * 4);
    int*       cursor = (int*)alloc((size_t)N * 4);
    int*       elist  = (int*)alloc((size_t)E * 4);

    // weights + time embedding + node embedding
    prep_weights<<<(NCONV * HID * HID + 255) / 256, 256, 0, stream>>>(cW1, cW2, WABT, W2T);
    prep_enc<<<(HID * HID + 255) / 256, 256, 0, stream>>>(eW, encT);
    time_emb_kernel<<<1, 64, 0, stream>>>(t, tpW, tpb, temb);
    node_emb_kernel<<<N, HID, 0, stream>>>(x, temb, neW, neb, hA, N);

    // CSR by dst
    hipMemsetAsync(deg, 0, (size_t)N * 4, stream);
    count_deg<<<(E + 255) / 256, 256, 0, stream>>>(ei, deg, E);
    scan_csr<<<1, 1024, 0, stream>>>(deg, rowptr, cursor, N);
    fill_csr<<<(E + 255) / 256, 256, 0, stream>>>(ei, cursor, elist, E);

    int nmt = (N + 15) / 16;
    int ab_blocks = (nmt * 8 + 3) / 4;      // OUT=256 -> JW=8
    int fc_blocks = (nmt * 4 + 3) / 4;      // OUT=128 -> JW=4
    int ec_blocks = (N + 3) / 4;            // one node per wave

    _Float16* cur = hA;
    for (int l = 0; l < NCONV; l++) {
        if (l == 4) {
            gemm_h<128><<<fc_blocks, 256, 0, stream>>>(cur, encT, eb, hB, N);
            cur = hB;
        }
        gemm_h<256><<<ab_blocks, 256, 0, stream>>>(cur, WABT + (size_t)l * 2 * HID * HID,
                                                   cb1 + (size_t)l * HID, AB, N);
        edge_conv<<<ec_blocks, 256, 0, stream>>>(AB, W2T + (size_t)l * HID * HID,
                                                 cb2 + (size_t)l * HID, rowptr, elist, cur, N);
    }

    fc_dec<<<N, HID, 0, stream>>>(cur, dW, db, (float*)d_out, N);
}

// Round 4
// 422.305 us; speedup vs baseline: 2.3502x; 2.2575x over previous
//
#include <hip/hip_runtime.h>
#include <hip/hip_fp16.h>

typedef _Float16 half8 __attribute__((ext_vector_type(8)));
typedef float f32x4 __attribute__((ext_vector_type(4)));

#define HID 128
#define NDIM 16
#define NCONV 8

static __device__ __forceinline__ half8 load_h8(const _Float16* p) {
    return *(const half8*)p;
}

// ---------------- weight prep: f16 transposed weights ----------------
// WABT[l] : [256][128] f16. rows j<128:  W1A_T[j][k] = W1[l][k][j] - W1[l][128+k][j]
//                           rows 128+j:  W1B_T[j][k] = W1[l][128+k][j]
// W2T[l]  : [128][128] f16. W2T[j][k] = W2[l][k][j]
__global__ void prep_weights(const float* __restrict__ W1, const float* __restrict__ W2,
                             _Float16* __restrict__ WABT, _Float16* __restrict__ W2T) {
    int idx = blockIdx.x * blockDim.x + threadIdx.x;
    int total = NCONV * HID * HID;
    if (idx >= total) return;
    int l = idx / (HID * HID);
    int r = idx % (HID * HID);
    int j = r / HID;
    int k = r % HID;
    const float* w1 = W1 + (size_t)l * 2 * HID * HID;
    float top = w1[k * HID + j];
    float bot = w1[(HID + k) * HID + j];
    _Float16* wab = WABT + (size_t)l * 2 * HID * HID;
    wab[j * HID + k] = (_Float16)(top - bot);
    wab[(HID + j) * HID + k] = (_Float16)bot;
    const float* w2 = W2 + (size_t)l * HID * HID;
    W2T[(size_t)l * HID * HID + j * HID + k] = (_Float16)w2[k * HID + j];
}

// enc_fc weight transpose -> f16: encT[j][k] = eW[k][j]
__global__ void prep_enc(const float* __restrict__ eW, _Float16* __restrict__ encT) {
    int idx = blockIdx.x * blockDim.x + threadIdx.x;
    if (idx >= HID * HID) return;
    int j = idx / HID;
    int k = idx % HID;
    encT[j * HID + k] = (_Float16)eW[k * HID + j];
}

// ---------------- time embedding ----------------
__global__ void time_emb_kernel(const float* __restrict__ t, const float* __restrict__ tpW,
                                const float* __restrict__ tpb, float* __restrict__ temb) {
    __shared__ float sc[64];
    int i = threadIdx.x;
    float tv = t[0];
    if (i < 32) {
        float f = expf(-4.0f + 8.0f * (float)i / 31.0f);
        sc[i] = sinf(tv * f);
        sc[32 + i] = cosf(tv * f);
    }
    __syncthreads();
    if (i < 16) {
        float acc = tpb[i];
        for (int k = 0; k < 64; k++) acc += sc[k] * tpW[k * NDIM + i];
        temb[i] = acc;
    }
}

// ---------------- node embedding: h = (x + temb) @ neW + neb -> f16 ----------------
__global__ void node_emb_kernel(const float* __restrict__ x, const float* __restrict__ temb,
                                const float* __restrict__ W, const float* __restrict__ b,
                                _Float16* __restrict__ h16, int n) {
    __shared__ float sx[NDIM];
    int node = blockIdx.x;
    if (node >= n) return;
    int j = threadIdx.x;
    if (j < NDIM) sx[j] = x[(size_t)node * NDIM + j] + temb[j];
    __syncthreads();
    float acc = b[j];
    #pragma unroll
    for (int d = 0; d < NDIM; d++) acc += sx[d] * W[d * HID + j];
    h16[(size_t)node * HID + j] = (_Float16)acc;
}

// ---------------- CSR build ----------------
__global__ void count_deg(const int* __restrict__ ei, int* __restrict__ deg, int E) {
    int e = blockIdx.x * blockDim.x + threadIdx.x;
    if (e < E) atomicAdd(&deg[ei[E + e]], 1);   // dst row
}

__global__ void scan_csr(const int* __restrict__ deg, int* __restrict__ rowptr,
                         int* __restrict__ cursor, int n) {
    __shared__ int part[1024];
    int t = threadIdx.x;
    int chunk = (n + 1023) / 1024;
    int base = t * chunk;
    int s = 0;
    for (int i = 0; i < chunk; i++) {
        int id = base + i;
        if (id < n) s += deg[id];
    }
    part[t] = s;
    __syncthreads();
    for (int off = 1; off < 1024; off <<= 1) {
        int v = 0;
        if (t >= off) v = part[t - off];
        __syncthreads();
        part[t] += v;
        __syncthreads();
    }
    int pre = (t == 0) ? 0 : part[t - 1];
    for (int i = 0; i < chunk; i++) {
        int id = base + i;
        if (id < n) {
            rowptr[id] = pre;
            cursor[id] = pre;
            pre += deg[id];
        }
    }
    if (t == 1023) rowptr[n] = part[1023];
}

__global__ void fill_csr(const int* __restrict__ ei, int* __restrict__ cursor,
                         int* __restrict__ elist, int E) {
    int e = blockIdx.x * blockDim.x + threadIdx.x;
    if (e < E) {
        int d = ei[E + e];
        int pos = atomicAdd(&cursor[d], 1);
        elist[pos] = ei[e];   // src
    }
}

// ---------------- generic node GEMM: Y[n][OUT] = A[n][128] @ WT^T + bias ----------------
template<int OUT>
__global__ __launch_bounds__(256) void gemm_h(const _Float16* __restrict__ A,
                                              const _Float16* __restrict__ WT,
                                              const float* __restrict__ bias,
                                              _Float16* __restrict__ Y, int n) {
    constexpr int JW = OUT / 32;    // j-pairs per m-tile
    int gw = (blockIdx.x * blockDim.x + threadIdx.x) >> 6;
    int lane = threadIdx.x & 63;
    int nmt = (n + 15) >> 4;
    if (gw >= nmt * JW) return;
    int mt = gw / JW;
    int jp = gw % JW;
    int c = lane & 15;
    int kq = lane >> 4;

    int arow = mt * 16 + c;
    half8 a[4];
    #pragma unroll
    for (int kb = 0; kb < 4; kb++) {
        if (arow < n) a[kb] = load_h8(A + (size_t)arow * HID + kb * 32 + kq * 8);
        else          a[kb] = (half8)(_Float16)0;
    }

    f32x4 acc[2];
    #pragma unroll
    for (int p = 0; p < 2; p++) {
        acc[p][0] = 0.f; acc[p][1] = 0.f; acc[p][2] = 0.f; acc[p][3] = 0.f;
        int wrow = (jp * 2 + p) * 16 + c;
        #pragma unroll
        for (int kb = 0; kb < 4; kb++) {
            half8 b = load_h8(WT + (size_t)wrow * HID + kb * 32 + kq * 8);
            acc[p] = __builtin_amdgcn_mfma_f32_16x16x32_f16(a[kb], b, acc[p], 0, 0, 0);
        }
    }

    #pragma unroll
    for (int p = 0; p < 2; p++) {
        int col = (jp * 2 + p) * 16 + c;
        float bv = (col < HID) ? bias[col] : 0.f;
        #pragma unroll
        for (int r = 0; r < 4; r++) {
            int row = mt * 16 + kq * 4 + r;
            if (row < n) Y[(size_t)row * OUT + col] = (_Float16)(acc[p][r] + bv);
        }
    }
}

// ---------------- EdgeConv: out[v][j] = max_e relu(A[v]+B[src_e]) @ W2 + b2 ----------------
// One node per wave. W2 in LDS, FRAGMENT-MAJOR layout: frag(kb,cb,lane) at
// ((kb*8+cb)*64+lane)*16B -> every ds_read_b128 is lane-consecutive (0 conflicts,
// verified r3: SQ_LDS_BANK_CONFLICT=0).
// NOTE: no min-waves launch bound — forcing 4 waves/EU (r2/r3) capped the unified
// reg budget at 128 and generated ~200 MB/dispatch of scratch spill traffic.
__global__ __launch_bounds__(256) void edge_conv(const _Float16* __restrict__ AB,
                                                 const _Float16* __restrict__ W2T_l,
                                                 const float* __restrict__ b2_l,
                                                 const int* __restrict__ rowptr,
                                                 const int* __restrict__ elist,
                                                 _Float16* __restrict__ hout, int n) {
    __shared__ _Float16 w2s[2048 * 8];   // 2048 frags x 16B = 32 KB
    __shared__ float b2s[HID];
    int tid = threadIdx.x;
    #pragma unroll
    for (int i = 0; i < 8; i++) {
        int fid = i * 256 + tid;
        int c = fid & 15;
        int kq = (fid >> 4) & 3;
        int grp = fid >> 6;          // kb*8+cb
        int kb = grp >> 3;
        int cb = grp & 7;
        half8 v = load_h8(W2T_l + (size_t)(cb * 16 + c) * HID + kb * 32 + kq * 8);
        *(half8*)(w2s + (size_t)fid * 8) = v;
    }
    if (tid < HID) b2s[tid] = b2_l[tid];
    __syncthreads();

    int lane = tid & 63;
    int c = lane & 15;
    int kq = lane >> 4;
    int gw = (blockIdx.x * blockDim.x + tid) >> 6;
    int nw = (gridDim.x * blockDim.x) >> 6;

    for (int v = gw; v < n; v += nw) {
        int rbeg = rowptr[v];
        int deg = rowptr[v + 1] - rbeg;     // real in-edges; +1 implicit self-loop
        int ntile = (deg + 16) >> 4;        // ceil((deg+1)/16)

        half8 af[4];
        #pragma unroll
        for (int kb = 0; kb < 4; kb++)
            af[kb] = load_h8(AB + (size_t)v * 256 + kb * 32 + kq * 8);

        float macc[8];
        #pragma unroll
        for (int cb = 0; cb < 8; cb++) macc[cb] = -3.0e38f;

        for (int tI = 0; tI < ntile; tI++) {
            int gidx = tI * 16 + c;
            int src = (gidx < deg) ? elist[rbeg + gidx] : v;   // pad with self-loop

            // prefetch the 4 B fragments of this edge's row
            const _Float16* bp = AB + (size_t)src * 256 + 128 + kq * 8;
            half8 bs[4];
            #pragma unroll
            for (int kb = 0; kb < 4; kb++) bs[kb] = load_h8(bp + kb * 32);

            f32x4 d[8];
            #pragma unroll
            for (int cb = 0; cb < 8; cb++) { d[cb][0] = 0.f; d[cb][1] = 0.f; d[cb][2] = 0.f; d[cb][3] = 0.f; }

            #pragma unroll
            for (int kb = 0; kb < 4; kb++) {
                half8 s = af[kb] + bs[kb];
                #pragma unroll
                for (int e = 0; e < 8; e++) s[e] = (s[e] > (_Float16)0) ? s[e] : (_Float16)0;
                #pragma unroll
                for (int cb = 0; cb < 8; cb++) {
                    half8 w = *(const half8*)(w2s + ((size_t)((kb * 8 + cb) * 64 + lane)) * 8);
                    d[cb] = __builtin_amdgcn_mfma_f32_16x16x32_f16(s, w, d[cb], 0, 0, 0);
                }
            }
            #pragma unroll
            for (int cb = 0; cb < 8; cb++) {
                float m0 = fmaxf(fmaxf(d[cb][0], d[cb][1]), fmaxf(d[cb][2], d[cb][3]));
                macc[cb] = fmaxf(macc[cb], m0);
            }
        }

        #pragma unroll
        for (int cb = 0; cb < 8; cb++) {
            float m = macc[cb];
            m = fmaxf(m, __shfl_xor(m, 16));
            m = fmaxf(m, __shfl_xor(m, 32));
            m += b2s[cb * 16 + c];
            if (lane < 16) hout[(size_t)v * HID + cb * 16 + c] = (_Float16)m;
        }
    }
}

// ---------------- decoder FC: out = h @ dW + db  (fp32 out [N][16]) ----------------
__global__ void fc_dec(const _Float16* __restrict__ h16, const float* __restrict__ W,
                       const float* __restrict__ b, float* __restrict__ out, int n) {
    __shared__ float row[HID];
    __shared__ float part[64];
    int node = blockIdx.x;
    if (node >= n) return;
    int t = threadIdx.x;
    row[t] = (float)h16[(size_t)node * HID + t];
    row[64 + t] = (float)h16[(size_t)node * HID + 64 + t];
    __syncthreads();
    int j = t & 15;
    int ks = t >> 4;   // 0..3, each covers 32 k
    float p = 0.f;
    for (int k = ks * 32; k < ks * 32 + 32; k++) p += row[k] * W[k * NDIM + j];
    part[t] = p;
    __syncthreads();
    if (t < 16) {
        float o = b[j] + part[j] + part[16 + j] + part[32 + j] + part[48 + j];
        out[(size_t)node * NDIM + j] = o;
    }
}

// ---------------- host ----------------
extern "C" void kernel_launch(void* const* d_in, const int* in_sizes, int n_in,
                              void* d_out, int out_size, void* d_ws, size_t ws_size,
                              hipStream_t stream) {
    const float* x   = (const float*)d_in[0];
    const int*   ei  = (const int*)d_in[1];
    const float* t   = (const float*)d_in[2];
    const float* neW = (const float*)d_in[3];
    const float* neb = (const float*)d_in[4];
    const float* cW1 = (const float*)d_in[5];
    const float* cb1 = (const float*)d_in[6];
    const float* cW2 = (const float*)d_in[7];
    const float* cb2 = (const float*)d_in[8];
    const float* eW  = (const float*)d_in[9];
    const float* eb  = (const float*)d_in[10];
    const float* dW  = (const float*)d_in[11];
    const float* db  = (const float*)d_in[12];
    const float* tpW = (const float*)d_in[13];
    const float* tpb = (const float*)d_in[14];

    int N = in_sizes[0] / NDIM;
    int E = in_sizes[1] / 2;

    char* w = (char*)d_ws;
    auto alloc = [&](size_t bytes) {
        void* p = (void*)w;
        w += (bytes + 255) & ~(size_t)255;
        return p;
    };
    float*     temb   = (float*)alloc(64 * 4);
    _Float16*  hA     = (_Float16*)alloc((size_t)N * HID * 2);
    _Float16*  hB     = (_Float16*)alloc((size_t)N * HID * 2);
    _Float16*  AB     = (_Float16*)alloc((size_t)N * 2 * HID * 2);
    _Float16*  WABT   = (_Float16*)alloc((size_t)NCONV * 2 * HID * HID * 2);
    _Float16*  W2T    = (_Float16*)alloc((size_t)NCONV * HID * HID * 2);
    _Float16*  encT   = (_Float16*)alloc((size_t)HID * HID * 2);
    int*       deg    = (int*)alloc((size_t)N * 4);
    int*       rowptr = (int*)alloc((size_t)(N + 1) * 4);
    int*       cursor = (int*)alloc((size_t)N * 4);
    int*       elist  = (int*)alloc((size_t)E * 4);

    // weights + time embedding + node embedding
    prep_weights<<<(NCONV * HID * HID + 255) / 256, 256, 0, stream>>>(cW1, cW2, WABT, W2T);
    prep_enc<<<(HID * HID + 255) / 256, 256, 0, stream>>>(eW, encT);
    time_emb_kernel<<<1, 64, 0, stream>>>(t, tpW, tpb, temb);
    node_emb_kernel<<<N, HID, 0, stream>>>(x, temb, neW, neb, hA, N);

    // CSR by dst
    hipMemsetAsync(deg, 0, (size_t)N * 4, stream);
    count_deg<<<(E + 255) / 256, 256, 0, stream>>>(ei, deg, E);
    scan_csr<<<1, 1024, 0, stream>>>(deg, rowptr, cursor, N);
    fill_csr<<<(E + 255) / 256, 256, 0, stream>>>(ei, cursor, elist, E);

    int nmt = (N + 15) / 16;
    int ab_blocks = (nmt * 8 + 3) / 4;      // OUT=256 -> JW=8
    int fc_blocks = (nmt * 4 + 3) / 4;      // OUT=128 -> JW=4
    int ec_blocks = (N + 3) / 4;            // one node per wave

    _Float16* cur = hA;
    for (int l = 0; l < NCONV; l++) {
        if (l == 4) {
            gemm_h<128><<<fc_blocks, 256, 0, stream>>>(cur, encT, eb, hB, N);
            cur = hB;
        }
        gemm_h<256><<<ab_blocks, 256, 0, stream>>>(cur, WABT + (size_t)l * 2 * HID * HID,
                                                   cb1 + (size_t)l * HID, AB, N);
        edge_conv<<<ec_blocks, 256, 0, stream>>>(AB, W2T + (size_t)l * HID * HID,
                                                 cb2 + (size_t)l * HID, rowptr, elist, cur, N);
    }

    fc_dec<<<N, HID, 0, stream>>>(cur, dW, db, (float*)d_out, N);
}

// Round 5
// 358.479 us; speedup vs baseline: 2.7687x; 1.1780x over previous
//
#include <hip/hip_runtime.h>
#include <hip/hip_fp16.h>

typedef _Float16 half8 __attribute__((ext_vector_type(8)));
typedef float f32x4 __attribute__((ext_vector_type(4)));

#define HID 128
#define NDIM 16
#define NCONV 8

static __device__ __forceinline__ half8 load_h8(const _Float16* p) {
    return *(const half8*)p;
}

// ---------------- weight prep: f16 transposed weights ----------------
// WABT[l] : [256][128] f16. rows j<128:  W1A_T[j][k] = W1[l][k][j] - W1[l][128+k][j]
//                           rows 128+j:  W1B_T[j][k] = W1[l][128+k][j]
// W2T[l]  : [128][128] f16. W2T[j][k] = W2[l][k][j]
__global__ void prep_weights(const float* __restrict__ W1, const float* __restrict__ W2,
                             _Float16* __restrict__ WABT, _Float16* __restrict__ W2T) {
    int idx = blockIdx.x * blockDim.x + threadIdx.x;
    int total = NCONV * HID * HID;
    if (idx >= total) return;
    int l = idx / (HID * HID);
    int r = idx % (HID * HID);
    int j = r / HID;
    int k = r % HID;
    const float* w1 = W1 + (size_t)l * 2 * HID * HID;
    float top = w1[k * HID + j];
    float bot = w1[(HID + k) * HID + j];
    _Float16* wab = WABT + (size_t)l * 2 * HID * HID;
    wab[j * HID + k] = (_Float16)(top - bot);
    wab[(HID + j) * HID + k] = (_Float16)bot;
    const float* w2 = W2 + (size_t)l * HID * HID;
    W2T[(size_t)l * HID * HID + j * HID + k] = (_Float16)w2[k * HID + j];
}

// enc_fc weight transpose -> f16: encT[j][k] = eW[k][j]
__global__ void prep_enc(const float* __restrict__ eW, _Float16* __restrict__ encT) {
    int idx = blockIdx.x * blockDim.x + threadIdx.x;
    if (idx >= HID * HID) return;
    int j = idx / HID;
    int k = idx % HID;
    encT[j * HID + k] = (_Float16)eW[k * HID + j];
}

// ---------------- time embedding ----------------
__global__ void time_emb_kernel(const float* __restrict__ t, const float* __restrict__ tpW,
                                const float* __restrict__ tpb, float* __restrict__ temb) {
    __shared__ float sc[64];
    int i = threadIdx.x;
    float tv = t[0];
    if (i < 32) {
        float f = expf(-4.0f + 8.0f * (float)i / 31.0f);
        sc[i] = sinf(tv * f);
        sc[32 + i] = cosf(tv * f);
    }
    __syncthreads();
    if (i < 16) {
        float acc = tpb[i];
        for (int k = 0; k < 64; k++) acc += sc[k] * tpW[k * NDIM + i];
        temb[i] = acc;
    }
}

// ---------------- node embedding: h = (x + temb) @ neW + neb -> f16 ----------------
__global__ void node_emb_kernel(const float* __restrict__ x, const float* __restrict__ temb,
                                const float* __restrict__ W, const float* __restrict__ b,
                                _Float16* __restrict__ h16, int n) {
    __shared__ float sx[NDIM];
    int node = blockIdx.x;
    if (node >= n) return;
    int j = threadIdx.x;
    if (j < NDIM) sx[j] = x[(size_t)node * NDIM + j] + temb[j];
    __syncthreads();
    float acc = b[j];
    #pragma unroll
    for (int d = 0; d < NDIM; d++) acc += sx[d] * W[d * HID + j];
    h16[(size_t)node * HID + j] = (_Float16)acc;
}

// ---------------- CSR build ----------------
__global__ void count_deg(const int* __restrict__ ei, int* __restrict__ deg, int E) {
    int e = blockIdx.x * blockDim.x + threadIdx.x;
    if (e < E) atomicAdd(&deg[ei[E + e]], 1);   // dst row
}

__global__ void scan_csr(const int* __restrict__ deg, int* __restrict__ rowptr,
                         int* __restrict__ cursor, int n) {
    __shared__ int part[1024];
    int t = threadIdx.x;
    int chunk = (n + 1023) / 1024;
    int base = t * chunk;
    int s = 0;
    for (int i = 0; i < chunk; i++) {
        int id = base + i;
        if (id < n) s += deg[id];
    }
    part[t] = s;
    __syncthreads();
    for (int off = 1; off < 1024; off <<= 1) {
        int v = 0;
        if (t >= off) v = part[t - off];
        __syncthreads();
        part[t] += v;
        __syncthreads();
    }
    int pre = (t == 0) ? 0 : part[t - 1];
    for (int i = 0; i < chunk; i++) {
        int id = base + i;
        if (id < n) {
            rowptr[id] = pre;
            cursor[id] = pre;
            pre += deg[id];
        }
    }
    if (t == 1023) rowptr[n] = part[1023];
}

__global__ void fill_csr(const int* __restrict__ ei, int* __restrict__ cursor,
                         int* __restrict__ elist, int E) {
    int e = blockIdx.x * blockDim.x + threadIdx.x;
    if (e < E) {
        int d = ei[E + e];
        int pos = atomicAdd(&cursor[d], 1);
        elist[pos] = ei[e];   // src
    }
}

// ---------------- generic node GEMM: Y[n][OUT] = A[n][128] @ WT^T + bias ----------------
template<int OUT>
__global__ __launch_bounds__(256) void gemm_h(const _Float16* __restrict__ A,
                                              const _Float16* __restrict__ WT,
                                              const float* __restrict__ bias,
                                              _Float16* __restrict__ Y, int n) {
    constexpr int JW = OUT / 32;    // j-pairs per m-tile
    int gw = (blockIdx.x * blockDim.x + threadIdx.x) >> 6;
    int lane = threadIdx.x & 63;
    int nmt = (n + 15) >> 4;
    if (gw >= nmt * JW) return;
    int mt = gw / JW;
    int jp = gw % JW;
    int c = lane & 15;
    int kq = lane >> 4;

    int arow = mt * 16 + c;
    half8 a[4];
    #pragma unroll
    for (int kb = 0; kb < 4; kb++) {
        if (arow < n) a[kb] = load_h8(A + (size_t)arow * HID + kb * 32 + kq * 8);
        else          a[kb] = (half8)(_Float16)0;
    }

    f32x4 acc[2];
    #pragma unroll
    for (int p = 0; p < 2; p++) {
        acc[p][0] = 0.f; acc[p][1] = 0.f; acc[p][2] = 0.f; acc[p][3] = 0.f;
        int wrow = (jp * 2 + p) * 16 + c;
        #pragma unroll
        for (int kb = 0; kb < 4; kb++) {
            half8 b = load_h8(WT + (size_t)wrow * HID + kb * 32 + kq * 8);
            acc[p] = __builtin_amdgcn_mfma_f32_16x16x32_f16(a[kb], b, acc[p], 0, 0, 0);
        }
    }

    #pragma unroll
    for (int p = 0; p < 2; p++) {
        int col = (jp * 2 + p) * 16 + c;
        float bv = (col < HID) ? bias[col] : 0.f;
        #pragma unroll
        for (int r = 0; r < 4; r++) {
            int row = mt * 16 + kq * 4 + r;
            if (row < n) Y[(size_t)row * OUT + col] = (_Float16)(acc[p][r] + bv);
        }
    }
}

// ---------------- EdgeConv: out[v][j] = max_e relu(A[v]+B[src_e]) @ W2 + b2 ----------------
// Grid-stride, grid == resident capacity (1024 blocks = 4/CU x 256 CU, LDS-capped)
// so W2 staging is amortized over ~2.4 nodes/wave and there is one scheduling pass.
// W2 in LDS, FRAGMENT-MAJOR layout: frag(kb,cb,lane) at ((kb*8+cb)*64+lane)*16B ->
// every ds_read_b128 is lane-consecutive (0 conflicts, verified r3).
// elist indices for tile i+1 are prefetched before tile i's MFMAs (1 extra VGPR).
// NOTE: no min-waves launch bound — forcing 4 waves/EU (r2/r3) capped the unified
// reg budget at 128 and generated ~200 MB/dispatch of scratch spill traffic.
__global__ __launch_bounds__(256) void edge_conv(const _Float16* __restrict__ AB,
                                                 const _Float16* __restrict__ W2T_l,
                                                 const float* __restrict__ b2_l,
                                                 const int* __restrict__ rowptr,
                                                 const int* __restrict__ elist,
                                                 _Float16* __restrict__ hout, int n) {
    __shared__ _Float16 w2s[2048 * 8];   // 2048 frags x 16B = 32 KB
    __shared__ float b2s[HID];
    int tid = threadIdx.x;
    #pragma unroll
    for (int i = 0; i < 8; i++) {
        int fid = i * 256 + tid;
        int c = fid & 15;
        int kq = (fid >> 4) & 3;
        int grp = fid >> 6;          // kb*8+cb
        int kb = grp >> 3;
        int cb = grp & 7;
        half8 v = load_h8(W2T_l + (size_t)(cb * 16 + c) * HID + kb * 32 + kq * 8);
        *(half8*)(w2s + (size_t)fid * 8) = v;
    }
    if (tid < HID) b2s[tid] = b2_l[tid];
    __syncthreads();

    int lane = tid & 63;
    int c = lane & 15;
    int kq = lane >> 4;
    int gw = (blockIdx.x * blockDim.x + tid) >> 6;
    int nw = (gridDim.x * blockDim.x) >> 6;

    for (int v = gw; v < n; v += nw) {
        int rbeg = rowptr[v];
        int deg = rowptr[v + 1] - rbeg;     // real in-edges; +1 implicit self-loop
        int ntile = (deg + 16) >> 4;        // ceil((deg+1)/16)

        half8 af[4];
        #pragma unroll
        for (int kb = 0; kb < 4; kb++)
            af[kb] = load_h8(AB + (size_t)v * 256 + kb * 32 + kq * 8);

        float macc[8];
        #pragma unroll
        for (int cb = 0; cb < 8; cb++) macc[cb] = -3.0e38f;

        // pipeline: src index for tile 0 loaded before the loop; tile i+1's index
        // is loaded before tile i's MFMA block so the elist latency hides.
        int src = (c < deg) ? elist[rbeg + c] : v;

        for (int tI = 0; tI < ntile; tI++) {
            // prefetch the 4 B fragments of this edge's row
            const _Float16* bp = AB + (size_t)src * 256 + 128 + kq * 8;
            half8 bs[4];
            #pragma unroll
            for (int kb = 0; kb < 4; kb++) bs[kb] = load_h8(bp + kb * 32);

            // prefetch next tile's src index (overlaps with MFMAs below)
            int gidxn = (tI + 1) * 16 + c;
            int srcn = (tI + 1 < ntile && gidxn < deg) ? elist[rbeg + gidxn] : v;

            f32x4 d[8];
            #pragma unroll
            for (int cb = 0; cb < 8; cb++) { d[cb][0] = 0.f; d[cb][1] = 0.f; d[cb][2] = 0.f; d[cb][3] = 0.f; }

            #pragma unroll
            for (int kb = 0; kb < 4; kb++) {
                half8 s = af[kb] + bs[kb];
                #pragma unroll
                for (int e = 0; e < 8; e++) s[e] = (s[e] > (_Float16)0) ? s[e] : (_Float16)0;
                #pragma unroll
                for (int cb = 0; cb < 8; cb++) {
                    half8 w = *(const half8*)(w2s + ((size_t)((kb * 8 + cb) * 64 + lane)) * 8);
                    d[cb] = __builtin_amdgcn_mfma_f32_16x16x32_f16(s, w, d[cb], 0, 0, 0);
                }
            }
            #pragma unroll
            for (int cb = 0; cb < 8; cb++) {
                float m0 = fmaxf(fmaxf(d[cb][0], d[cb][1]), fmaxf(d[cb][2], d[cb][3]));
                macc[cb] = fmaxf(macc[cb], m0);
            }
            src = srcn;
        }

        #pragma unroll
        for (int cb = 0; cb < 8; cb++) {
            float m = macc[cb];
            m = fmaxf(m, __shfl_xor(m, 16));
            m = fmaxf(m, __shfl_xor(m, 32));
            m += b2s[cb * 16 + c];
            if (lane < 16) hout[(size_t)v * HID + cb * 16 + c] = (_Float16)m;
        }
    }
}

// ---------------- decoder FC: out = h @ dW + db  (fp32 out [N][16]) ----------------
__global__ void fc_dec(const _Float16* __restrict__ h16, const float* __restrict__ W,
                       const float* __restrict__ b, float* __restrict__ out, int n) {
    __shared__ float row[HID];
    __shared__ float part[64];
    int node = blockIdx.x;
    if (node >= n) return;
    int t = threadIdx.x;
    row[t] = (float)h16[(size_t)node * HID + t];
    row[64 + t] = (float)h16[(size_t)node * HID + 64 + t];
    __syncthreads();
    int j = t & 15;
    int ks = t >> 4;   // 0..3, each covers 32 k
    float p = 0.f;
    for (int k = ks * 32; k < ks * 32 + 32; k++) p += row[k] * W[k * NDIM + j];
    part[t] = p;
    __syncthreads();
    if (t < 16) {
        float o = b[j] + part[j] + part[16 + j] + part[32 + j] + part[48 + j];
        out[(size_t)node * NDIM + j] = o;
    }
}

// ---------------- host ----------------
extern "C" void kernel_launch(void* const* d_in, const int* in_sizes, int n_in,
                              void* d_out, int out_size, void* d_ws, size_t ws_size,
                              hipStream_t stream) {
    const float* x   = (const float*)d_in[0];
    const int*   ei  = (const int*)d_in[1];
    const float* t   = (const float*)d_in[2];
    const float* neW = (const float*)d_in[3];
    const float* neb = (const float*)d_in[4];
    const float* cW1 = (const float*)d_in[5];
    const float* cb1 = (const float*)d_in[6];
    const float* cW2 = (const float*)d_in[7];
    const float* cb2 = (const float*)d_in[8];
    const float* eW  = (const float*)d_in[9];
    const float* eb  = (const float*)d_in[10];
    const float* dW  = (const float*)d_in[11];
    const float* db  = (const float*)d_in[12];
    const float* tpW = (const float*)d_in[13];
    const float* tpb = (const float*)d_in[14];

    int N = in_sizes[0] / NDIM;
    int E = in_sizes[1] / 2;

    char* w = (char*)d_ws;
    auto alloc = [&](size_t bytes) {
        void* p = (void*)w;
        w += (bytes + 255) & ~(size_t)255;
        return p;
    };
    float*     temb   = (float*)alloc(64 * 4);
    _Float16*  hA     = (_Float16*)alloc((size_t)N * HID * 2);
    _Float16*  hB     = (_Float16*)alloc((size_t)N * HID * 2);
    _Float16*  AB     = (_Float16*)alloc((size_t)N * 2 * HID * 2);
    _Float16*  WABT   = (_Float16*)alloc((size_t)NCONV * 2 * HID * HID * 2);
    _Float16*  W2T    = (_Float16*)alloc((size_t)NCONV * HID * HID * 2);
    _Float16*  encT   = (_Float16*)alloc((size_t)HID * HID * 2);
    int*       deg    = (int*)alloc((size_t)N * 4);
    int*       rowptr = (int*)alloc((size_t)(N + 1) * 4);
    int*       cursor = (int*)alloc((size_t)N * 4);
    int*       elist  = (int*)alloc((size_t)E * 4);

    // weights + time embedding + node embedding
    prep_weights<<<(NCONV * HID * HID + 255) / 256, 256, 0, stream>>>(cW1, cW2, WABT, W2T);
    prep_enc<<<(HID * HID + 255) / 256, 256, 0, stream>>>(eW, encT);
    time_emb_kernel<<<1, 64, 0, stream>>>(t, tpW, tpb, temb);
    node_emb_kernel<<<N, HID, 0, stream>>>(x, temb, neW, neb, hA, N);

    // CSR by dst
    hipMemsetAsync(deg, 0, (size_t)N * 4, stream);
    count_deg<<<(E + 255) / 256, 256, 0, stream>>>(ei, deg, E);
    scan_csr<<<1, 1024, 0, stream>>>(deg, rowptr, cursor, N);
    fill_csr<<<(E + 255) / 256, 256, 0, stream>>>(ei, cursor, elist, E);

    int nmt = (N + 15) / 16;
    int ab_blocks = (nmt * 8 + 3) / 4;      // OUT=256 -> JW=8
    int fc_blocks = (nmt * 4 + 3) / 4;      // OUT=128 -> JW=4
    int ec_blocks = (N + 3) / 4;            // one node per wave worth of work
    if (ec_blocks > 1024) ec_blocks = 1024; // = resident capacity (4 blocks/CU LDS-capped)

    _Float16* cur = hA;
    for (int l = 0; l < NCONV; l++) {
        if (l == 4) {
            gemm_h<128><<<fc_blocks, 256, 0, stream>>>(cur, encT, eb, hB, N);
            cur = hB;
        }
        gemm_h<256><<<ab_blocks, 256, 0, stream>>>(cur, WABT + (size_t)l * 2 * HID * HID,
                                                   cb1 + (size_t)l * HID, AB, N);
        edge_conv<<<ec_blocks, 256, 0, stream>>>(AB, W2T + (size_t)l * HID * HID,
                                                 cb2 + (size_t)l * HID, rowptr, elist, cur, N);
    }

    fc_dec<<<N, HID, 0, stream>>>(cur, dW, db, (float*)d_out, N);
}

// Round 6
// 337.055 us; speedup vs baseline: 2.9446x; 1.0636x over previous
//
#include <hip/hip_runtime.h>
#include <hip/hip_fp16.h>

typedef _Float16 half8 __attribute__((ext_vector_type(8)));
typedef float f32x4 __attribute__((ext_vector_type(4)));

#define HID 128
#define NDIM 16
#define NCONV 8

static __device__ __forceinline__ half8 load_h8(const _Float16* p) {
    return *(const half8*)p;
}

// ---------------- weight prep: f16 transposed weights ----------------
// WABT[l] : [256][128] f16. rows j<128:  W1A_T[j][k] = W1[l][k][j] - W1[l][128+k][j]
//                           rows 128+j:  W1B_T[j][k] = W1[l][128+k][j]
// W2T[l]  : [128][128] f16. W2T[j][k] = W2[l][k][j]
// tail range: encT[j][k] = eW[k][j]
__global__ void prep_weights(const float* __restrict__ W1, const float* __restrict__ W2,
                             const float* __restrict__ eW,
                             _Float16* __restrict__ WABT, _Float16* __restrict__ W2T,
                             _Float16* __restrict__ encT) {
    int idx = blockIdx.x * blockDim.x + threadIdx.x;
    int total = NCONV * HID * HID;
    if (idx < total) {
        int l = idx / (HID * HID);
        int r = idx % (HID * HID);
        int j = r / HID;
        int k = r % HID;
        const float* w1 = W1 + (size_t)l * 2 * HID * HID;
        float top = w1[k * HID + j];
        float bot = w1[(HID + k) * HID + j];
        _Float16* wab = WABT + (size_t)l * 2 * HID * HID;
        wab[j * HID + k] = (_Float16)(top - bot);
        wab[(HID + j) * HID + k] = (_Float16)bot;
        const float* w2 = W2 + (size_t)l * HID * HID;
        W2T[(size_t)l * HID * HID + j * HID + k] = (_Float16)w2[k * HID + j];
    } else if (idx < total + HID * HID) {
        int r = idx - total;
        int j = r / HID;
        int k = r % HID;
        encT[j * HID + k] = (_Float16)eW[k * HID + j];
    }
}

// ---------------- time embedding ----------------
__global__ void time_emb_kernel(const float* __restrict__ t, const float* __restrict__ tpW,
                                const float* __restrict__ tpb, float* __restrict__ temb) {
    __shared__ float sc[64];
    int i = threadIdx.x;
    float tv = t[0];
    if (i < 32) {
        float f = expf(-4.0f + 8.0f * (float)i / 31.0f);
        sc[i] = sinf(tv * f);
        sc[32 + i] = cosf(tv * f);
    }
    __syncthreads();
    if (i < 16) {
        float acc = tpb[i];
        for (int k = 0; k < 64; k++) acc += sc[k] * tpW[k * NDIM + i];
        temb[i] = acc;
    }
}

// ---------------- node embedding: h = (x + temb) @ neW + neb -> f16 ----------------
__global__ void node_emb_kernel(const float* __restrict__ x, const float* __restrict__ temb,
                                const float* __restrict__ W, const float* __restrict__ b,
                                _Float16* __restrict__ h16, int n) {
    __shared__ float sx[NDIM];
    int node = blockIdx.x;
    if (node >= n) return;
    int j = threadIdx.x;
    if (j < NDIM) sx[j] = x[(size_t)node * NDIM + j] + temb[j];
    __syncthreads();
    float acc = b[j];
    #pragma unroll
    for (int d = 0; d < NDIM; d++) acc += sx[d] * W[d * HID + j];
    h16[(size_t)node * HID + j] = (_Float16)acc;
}

// ---------------- CSR build ----------------
__global__ void count_deg(const int* __restrict__ ei, int* __restrict__ deg, int E) {
    int e = blockIdx.x * blockDim.x + threadIdx.x;
    if (e < E) atomicAdd(&deg[ei[E + e]], 1);   // dst row
}

__global__ void scan_csr(const int* __restrict__ deg, int* __restrict__ rowptr,
                         int* __restrict__ cursor, int n) {
    __shared__ int part[1024];
    int t = threadIdx.x;
    int chunk = (n + 1023) / 1024;
    int base = t * chunk;
    int s = 0;
    for (int i = 0; i < chunk; i++) {
        int id = base + i;
        if (id < n) s += deg[id];
    }
    part[t] = s;
    __syncthreads();
    for (int off = 1; off < 1024; off <<= 1) {
        int v = 0;
        if (t >= off) v = part[t - off];
        __syncthreads();
        part[t] += v;
        __syncthreads();
    }
    int pre = (t == 0) ? 0 : part[t - 1];
    for (int i = 0; i < chunk; i++) {
        int id = base + i;
        if (id < n) {
            rowptr[id] = pre;
            cursor[id] = pre;
            pre += deg[id];
        }
    }
    if (t == 1023) rowptr[n] = part[1023];
}

__global__ void fill_csr(const int* __restrict__ ei, int* __restrict__ cursor,
                         int* __restrict__ elist, int E) {
    int e = blockIdx.x * blockDim.x + threadIdx.x;
    if (e < E) {
        int d = ei[E + e];
        int pos = atomicAdd(&cursor[d], 1);
        elist[pos] = ei[e];   // src
    }
}

// ---------------- generic node GEMM: Y[n][OUT] = A[n][128] @ WT^T + bias ----------------
template<int OUT>
__global__ __launch_bounds__(256) void gemm_h(const _Float16* __restrict__ A,
                                              const _Float16* __restrict__ WT,
                                              const float* __restrict__ bias,
                                              _Float16* __restrict__ Y, int n) {
    constexpr int JW = OUT / 32;    // j-pairs per m-tile
    int gw = (blockIdx.x * blockDim.x + threadIdx.x) >> 6;
    int lane = threadIdx.x & 63;
    int nmt = (n + 15) >> 4;
    if (gw >= nmt * JW) return;
    int mt = gw / JW;
    int jp = gw % JW;
    int c = lane & 15;
    int kq = lane >> 4;

    int arow = mt * 16 + c;
    half8 a[4];
    #pragma unroll
    for (int kb = 0; kb < 4; kb++) {
        if (arow < n) a[kb] = load_h8(A + (size_t)arow * HID + kb * 32 + kq * 8);
        else          a[kb] = (half8)(_Float16)0;
    }

    f32x4 acc[2];
    #pragma unroll
    for (int p = 0; p < 2; p++) {
        acc[p][0] = 0.f; acc[p][1] = 0.f; acc[p][2] = 0.f; acc[p][3] = 0.f;
        int wrow = (jp * 2 + p) * 16 + c;
        #pragma unroll
        for (int kb = 0; kb < 4; kb++) {
            half8 b = load_h8(WT + (size_t)wrow * HID + kb * 32 + kq * 8);
            acc[p] = __builtin_amdgcn_mfma_f32_16x16x32_f16(a[kb], b, acc[p], 0, 0, 0);
        }
    }

    #pragma unroll
    for (int p = 0; p < 2; p++) {
        int col = (jp * 2 + p) * 16 + c;
        float bv = (col < HID) ? bias[col] : 0.f;
        #pragma unroll
        for (int r = 0; r < 4; r++) {
            int row = mt * 16 + kq * 4 + r;
            if (row < n) Y[(size_t)row * OUT + col] = (_Float16)(acc[p][r] + bv);
        }
    }
}

// ---------------- EdgeConv: out[v][j] = max_e relu(A[v]+B[src_e]) @ W2 + b2 ----------------
// 512-thread blocks (8 waves amortize one 32 KB W2 staging), grid 512 = 2 blocks/CU.
// W2 in LDS, FRAGMENT-MAJOR layout -> every ds_read_b128 lane-consecutive (0 conflicts, r3).
// Cross-node 2-deep software pipeline: while computing node v, the NEXT node's
// rowptr/deg are already in regs, its af fragments + first-tile src indices were
// issued one full node-computation earlier -> per-node serial latency chain
// (rowptr -> elist -> gather) collapses to ~0 in steady state.
// NOTE: no min-waves launch bound (r2/r3 lesson: forced budget -> 200 MB spills).
__global__ __launch_bounds__(512) void edge_conv(const _Float16* __restrict__ AB,
                                                 const _Float16* __restrict__ W2T_l,
                                                 const float* __restrict__ b2_l,
                                                 const int* __restrict__ rowptr,
                                                 const int* __restrict__ elist,
                                                 _Float16* __restrict__ hout, int n) {
    __shared__ _Float16 w2s[2048 * 8];   // 2048 frags x 16B = 32 KB
    __shared__ float b2s[HID];
    int tid = threadIdx.x;
    #pragma unroll
    for (int i = 0; i < 4; i++) {
        int fid = i * 512 + tid;
        int fc = fid & 15;
        int fkq = (fid >> 4) & 3;
        int grp = fid >> 6;          // kb*8+cb
        int fkb = grp >> 3;
        int fcb = grp & 7;
        *(half8*)(w2s + (size_t)fid * 8) =
            load_h8(W2T_l + (size_t)(fcb * 16 + fc) * HID + fkb * 32 + fkq * 8);
    }
    if (tid < HID) b2s[tid] = b2_l[tid];
    __syncthreads();

    int lane = tid & 63;
    int c = lane & 15;
    int kq = lane >> 4;
    int gw = (blockIdx.x * blockDim.x + tid) >> 6;
    int nw = (gridDim.x * blockDim.x) >> 6;
    if (gw >= n) return;

    // ---- pipeline prologue: node0 fully, node1's rowptr ----
    int v = gw;
    int rbeg0 = rowptr[v];
    int deg0 = rowptr[v + 1] - rbeg0;
    half8 af0[4];
    #pragma unroll
    for (int kb = 0; kb < 4; kb++)
        af0[kb] = load_h8(AB + (size_t)v * 256 + kb * 32 + kq * 8);
    int src0 = (c < deg0) ? elist[rbeg0 + c] : v;
    int v1 = v + nw;
    int rbeg1 = 0, deg1 = 0;
    if (v1 < n) { rbeg1 = rowptr[v1]; deg1 = rowptr[v1 + 1] - rbeg1; }

    while (true) {
        int vn = v + nw;
        int vn2 = vn + nw;
        // issue next-next rowptr, next af, next first-src NOW (overlap with compute)
        int rbeg2 = 0, deg2 = 0;
        if (vn2 < n) { rbeg2 = rowptr[vn2]; deg2 = rowptr[vn2 + 1] - rbeg2; }
        half8 af1[4];
        if (vn < n) {
            #pragma unroll
            for (int kb = 0; kb < 4; kb++)
                af1[kb] = load_h8(AB + (size_t)vn * 256 + kb * 32 + kq * 8);
        }
        int src1 = (c < deg1) ? elist[rbeg1 + c] : vn;

        // ---- compute current node ----
        int ntile = (deg0 + 16) >> 4;        // ceil((deg0+1)/16), pad = self-loop
        float macc[8];
        #pragma unroll
        for (int cb = 0; cb < 8; cb++) macc[cb] = -3.0e38f;

        int src = src0;
        for (int tI = 0; tI < ntile; tI++) {
            const _Float16* bp = AB + (size_t)src * 256 + 128 + kq * 8;
            half8 bs[4];
            #pragma unroll
            for (int kb = 0; kb < 4; kb++) bs[kb] = load_h8(bp + kb * 32);

            int gidxn = (tI + 1) * 16 + c;
            int srcn = (tI + 1 < ntile && gidxn < deg0) ? elist[rbeg0 + gidxn] : v;

            f32x4 d[8];
            #pragma unroll
            for (int cb = 0; cb < 8; cb++) { d[cb][0] = 0.f; d[cb][1] = 0.f; d[cb][2] = 0.f; d[cb][3] = 0.f; }

            #pragma unroll
            for (int kb = 0; kb < 4; kb++) {
                half8 s = af0[kb] + bs[kb];
                #pragma unroll
                for (int e = 0; e < 8; e++) s[e] = (s[e] > (_Float16)0) ? s[e] : (_Float16)0;
                #pragma unroll
                for (int cb = 0; cb < 8; cb++) {
                    half8 w = *(const half8*)(w2s + ((size_t)((kb * 8 + cb) * 64 + lane)) * 8);
                    d[cb] = __builtin_amdgcn_mfma_f32_16x16x32_f16(s, w, d[cb], 0, 0, 0);
                }
            }
            #pragma unroll
            for (int cb = 0; cb < 8; cb++) {
                float m0 = fmaxf(fmaxf(d[cb][0], d[cb][1]), fmaxf(d[cb][2], d[cb][3]));
                macc[cb] = fmaxf(macc[cb], m0);
            }
            src = srcn;
        }

        #pragma unroll
        for (int cb = 0; cb < 8; cb++) {
            float m = macc[cb];
            m = fmaxf(m, __shfl_xor(m, 16));
            m = fmaxf(m, __shfl_xor(m, 32));
            m += b2s[cb * 16 + c];
            if (lane < 16) hout[(size_t)v * HID + cb * 16 + c] = (_Float16)m;
        }

        // ---- rotate pipeline ----
        v = vn;
        if (v >= n) break;
        #pragma unroll
        for (int kb = 0; kb < 4; kb++) af0[kb] = af1[kb];
        src0 = src1;
        rbeg0 = rbeg1; deg0 = deg1;
        rbeg1 = rbeg2; deg1 = deg2;
    }
}

// ---------------- decoder FC: out = h @ dW + db  (fp32 out [N][16]) ----------------
__global__ void fc_dec(const _Float16* __restrict__ h16, const float* __restrict__ W,
                       const float* __restrict__ b, float* __restrict__ out, int n) {
    __shared__ float row[HID];
    __shared__ float part[64];
    int node = blockIdx.x;
    if (node >= n) return;
    int t = threadIdx.x;
    row[t] = (float)h16[(size_t)node * HID + t];
    row[64 + t] = (float)h16[(size_t)node * HID + 64 + t];
    __syncthreads();
    int j = t & 15;
    int ks = t >> 4;   // 0..3, each covers 32 k
    float p = 0.f;
    for (int k = ks * 32; k < ks * 32 + 32; k++) p += row[k] * W[k * NDIM + j];
    part[t] = p;
    __syncthreads();
    if (t < 16) {
        float o = b[j] + part[j] + part[16 + j] + part[32 + j] + part[48 + j];
        out[(size_t)node * NDIM + j] = o;
    }
}

// ---------------- host ----------------
extern "C" void kernel_launch(void* const* d_in, const int* in_sizes, int n_in,
                              void* d_out, int out_size, void* d_ws, size_t ws_size,
                              hipStream_t stream) {
    const float* x   = (const float*)d_in[0];
    const int*   ei  = (const int*)d_in[1];
    const float* t   = (const float*)d_in[2];
    const float* neW = (const float*)d_in[3];
    const float* neb = (const float*)d_in[4];
    const float* cW1 = (const float*)d_in[5];
    const float* cb1 = (const float*)d_in[6];
    const float* cW2 = (const float*)d_in[7];
    const float* cb2 = (const float*)d_in[8];
    const float* eW  = (const float*)d_in[9];
    const float* eb  = (const float*)d_in[10];
    const float* dW  = (const float*)d_in[11];
    const float* db  = (const float*)d_in[12];
    const float* tpW = (const float*)d_in[13];
    const float* tpb = (const float*)d_in[14];

    int N = in_sizes[0] / NDIM;
    int E = in_sizes[1] / 2;

    char* w = (char*)d_ws;
    auto alloc = [&](size_t bytes) {
        void* p = (void*)w;
        w += (bytes + 255) & ~(size_t)255;
        return p;
    };
    float*     temb   = (float*)alloc(64 * 4);
    _Float16*  hA     = (_Float16*)alloc((size_t)N * HID * 2);
    _Float16*  hB     = (_Float16*)alloc((size_t)N * HID * 2);
    _Float16*  AB     = (_Float16*)alloc((size_t)N * 2 * HID * 2);
    _Float16*  WABT   = (_Float16*)alloc((size_t)NCONV * 2 * HID * HID * 2);
    _Float16*  W2T    = (_Float16*)alloc((size_t)NCONV * HID * HID * 2);
    _Float16*  encT   = (_Float16*)alloc((size_t)HID * HID * 2);
    int*       deg    = (int*)alloc((size_t)N * 4);
    int*       rowptr = (int*)alloc((size_t)(N + 1) * 4);
    int*       cursor = (int*)alloc((size_t)N * 4);
    int*       elist  = (int*)alloc((size_t)E * 4);

    // weights + time embedding + node embedding
    int prep_total = NCONV * HID * HID + HID * HID;
    prep_weights<<<(prep_total + 255) / 256, 256, 0, stream>>>(cW1, cW2, eW, WABT, W2T, encT);
    time_emb_kernel<<<1, 64, 0, stream>>>(t, tpW, tpb, temb);
    node_emb_kernel<<<N, HID, 0, stream>>>(x, temb, neW, neb, hA, N);

    // CSR by dst
    hipMemsetAsync(deg, 0, (size_t)N * 4, stream);
    count_deg<<<(E + 255) / 256, 256, 0, stream>>>(ei, deg, E);
    scan_csr<<<1, 1024, 0, stream>>>(deg, rowptr, cursor, N);
    fill_csr<<<(E + 255) / 256, 256, 0, stream>>>(ei, cursor, elist, E);

    int nmt = (N + 15) / 16;
    int ab_blocks = (nmt * 8 + 3) / 4;      // OUT=256 -> JW=8
    int fc_blocks = (nmt * 4 + 3) / 4;      // OUT=128 -> JW=4
    int ec_blocks = 512;                    // 512 thr/block: 2 blocks/CU, 16 waves/CU

    _Float16* cur = hA;
    for (int l = 0; l < NCONV; l++) {
        if (l == 4) {
            gemm_h<128><<<fc_blocks, 256, 0, stream>>>(cur, encT, eb, hB, N);
            cur = hB;
        }
        gemm_h<256><<<ab_blocks, 256, 0, stream>>>(cur, WABT + (size_t)l * 2 * HID * HID,
                                                   cb1 + (size_t)l * HID, AB, N);
        edge_conv<<<ec_blocks, 512, 0, stream>>>(AB, W2T + (size_t)l * HID * HID,
                                                 cb2 + (size_t)l * HID, rowptr, elist, cur, N);
    }

    fc_dec<<<N, HID, 0, stream>>>(cur, dW, db, (float*)d_out, N);
}

// Round 7
// 336.320 us; speedup vs baseline: 2.9511x; 1.0022x over previous
//
#include <hip/hip_runtime.h>
#include <hip/hip_fp16.h>

typedef _Float16 half8 __attribute__((ext_vector_type(8)));
typedef float f32x4 __attribute__((ext_vector_type(4)));
typedef float f32x16 __attribute__((ext_vector_type(16)));

#define HID 128
#define NDIM 16
#define NCONV 8

static __device__ __forceinline__ half8 load_h8(const _Float16* p) {
    return *(const half8*)p;
}

// ---------------- weight prep: f16 transposed weights ----------------
// WABT[l] : [256][128] f16. rows j<128:  W1A_T[j][k] = W1[l][k][j] - W1[l][128+k][j]
//                           rows 128+j:  W1B_T[j][k] = W1[l][128+k][j]
// W2T[l]  : [128][128] f16. W2T[j][k] = W2[l][k][j]
// tail range: encT[j][k] = eW[k][j]
__global__ void prep_weights(const float* __restrict__ W1, const float* __restrict__ W2,
                             const float* __restrict__ eW,
                             _Float16* __restrict__ WABT, _Float16* __restrict__ W2T,
                             _Float16* __restrict__ encT) {
    int idx = blockIdx.x * blockDim.x + threadIdx.x;
    int total = NCONV * HID * HID;
    if (idx < total) {
        int l = idx / (HID * HID);
        int r = idx % (HID * HID);
        int j = r / HID;
        int k = r % HID;
        const float* w1 = W1 + (size_t)l * 2 * HID * HID;
        float top = w1[k * HID + j];
        float bot = w1[(HID + k) * HID + j];
        _Float16* wab = WABT + (size_t)l * 2 * HID * HID;
        wab[j * HID + k] = (_Float16)(top - bot);
        wab[(HID + j) * HID + k] = (_Float16)bot;
        const float* w2 = W2 + (size_t)l * HID * HID;
        W2T[(size_t)l * HID * HID + j * HID + k] = (_Float16)w2[k * HID + j];
    } else if (idx < total + HID * HID) {
        int r = idx - total;
        int j = r / HID;
        int k = r % HID;
        encT[j * HID + k] = (_Float16)eW[k * HID + j];
    }
}

// ---------------- time embedding ----------------
__global__ void time_emb_kernel(const float* __restrict__ t, const float* __restrict__ tpW,
                                const float* __restrict__ tpb, float* __restrict__ temb) {
    __shared__ float sc[64];
    int i = threadIdx.x;
    float tv = t[0];
    if (i < 32) {
        float f = expf(-4.0f + 8.0f * (float)i / 31.0f);
        sc[i] = sinf(tv * f);
        sc[32 + i] = cosf(tv * f);
    }
    __syncthreads();
    if (i < 16) {
        float acc = tpb[i];
        for (int k = 0; k < 64; k++) acc += sc[k] * tpW[k * NDIM + i];
        temb[i] = acc;
    }
}

// ---------------- node embedding: h = (x + temb) @ neW + neb -> f16 ----------------
__global__ void node_emb_kernel(const float* __restrict__ x, const float* __restrict__ temb,
                                const float* __restrict__ W, const float* __restrict__ b,
                                _Float16* __restrict__ h16, int n) {
    __shared__ float sx[NDIM];
    int node = blockIdx.x;
    if (node >= n) return;
    int j = threadIdx.x;
    if (j < NDIM) sx[j] = x[(size_t)node * NDIM + j] + temb[j];
    __syncthreads();
    float acc = b[j];
    #pragma unroll
    for (int d = 0; d < NDIM; d++) acc += sx[d] * W[d * HID + j];
    h16[(size_t)node * HID + j] = (_Float16)acc;
}

// ---------------- CSR build ----------------
__global__ void count_deg(const int* __restrict__ ei, int* __restrict__ deg, int E) {
    int e = blockIdx.x * blockDim.x + threadIdx.x;
    if (e < E) atomicAdd(&deg[ei[E + e]], 1);   // dst row
}

__global__ void scan_csr(const int* __restrict__ deg, int* __restrict__ rowptr,
                         int* __restrict__ cursor, int n) {
    __shared__ int part[1024];
    int t = threadIdx.x;
    int chunk = (n + 1023) / 1024;
    int base = t * chunk;
    int s = 0;
    for (int i = 0; i < chunk; i++) {
        int id = base + i;
        if (id < n) s += deg[id];
    }
    part[t] = s;
    __syncthreads();
    for (int off = 1; off < 1024; off <<= 1) {
        int v = 0;
        if (t >= off) v = part[t - off];
        __syncthreads();
        part[t] += v;
        __syncthreads();
    }
    int pre = (t == 0) ? 0 : part[t - 1];
    for (int i = 0; i < chunk; i++) {
        int id = base + i;
        if (id < n) {
            rowptr[id] = pre;
            cursor[id] = pre;
            pre += deg[id];
        }
    }
    if (t == 1023) rowptr[n] = part[1023];
}

__global__ void fill_csr(const int* __restrict__ ei, int* __restrict__ cursor,
                         int* __restrict__ elist, int E) {
    int e = blockIdx.x * blockDim.x + threadIdx.x;
    if (e < E) {
        int d = ei[E + e];
        int pos = atomicAdd(&cursor[d], 1);
        elist[pos] = ei[e];   // src
    }
}

// ---------------- generic node GEMM: Y[n][OUT] = A[n][128] @ WT^T + bias ----------------
template<int OUT>
__global__ __launch_bounds__(256) void gemm_h(const _Float16* __restrict__ A,
                                              const _Float16* __restrict__ WT,
                                              const float* __restrict__ bias,
                                              _Float16* __restrict__ Y, int n) {
    constexpr int JW = OUT / 32;    // j-pairs per m-tile
    int gw = (blockIdx.x * blockDim.x + threadIdx.x) >> 6;
    int lane = threadIdx.x & 63;
    int nmt = (n + 15) >> 4;
    if (gw >= nmt * JW) return;
    int mt = gw / JW;
    int jp = gw % JW;
    int c = lane & 15;
    int kq = lane >> 4;

    int arow = mt * 16 + c;
    half8 a[4];
    #pragma unroll
    for (int kb = 0; kb < 4; kb++) {
        if (arow < n) a[kb] = load_h8(A + (size_t)arow * HID + kb * 32 + kq * 8);
        else          a[kb] = (half8)(_Float16)0;
    }

    f32x4 acc[2];
    #pragma unroll
    for (int p = 0; p < 2; p++) {
        acc[p][0] = 0.f; acc[p][1] = 0.f; acc[p][2] = 0.f; acc[p][3] = 0.f;
        int wrow = (jp * 2 + p) * 16 + c;
        #pragma unroll
        for (int kb = 0; kb < 4; kb++) {
            half8 b = load_h8(WT + (size_t)wrow * HID + kb * 32 + kq * 8);
            acc[p] = __builtin_amdgcn_mfma_f32_16x16x32_f16(a[kb], b, acc[p], 0, 0, 0);
        }
    }

    #pragma unroll
    for (int p = 0; p < 2; p++) {
        int col = (jp * 2 + p) * 16 + c;
        float bv = (col < HID) ? bias[col] : 0.f;
        #pragma unroll
        for (int r = 0; r < 4; r++) {
            int row = mt * 16 + kq * 4 + r;
            if (row < n) Y[(size_t)row * OUT + col] = (_Float16)(acc[p][r] + bv);
        }
    }
}

// ---------------- EdgeConv: out[v][j] = max_e relu(A[v]+B[src_e]) @ W2 + b2 ----------------
// 32x32x16 MFMA, 32-edge tiles: avg deg+1=18 -> ~1 tile/node (vs 2 at 16-edge), halving
// LDS W2 traffic (the dominant pipe cost) + MFMA count + relu VALU per layer.
// A-frag: lane l = edge (l&31), k-slice (l>>5)*8+j. B-frag in LDS fragment-major,
// lane-consecutive 16B reads (0 conflicts). C cols = lane&31; per-cb f32x16 acc is
// collapsed to a scalar running max right after its K-loop (max over rows is
// layout-permutation-immune), keeping live regs ~105 < 128 -> 16 waves/CU.
// Cross-node pipeline: rowptr/deg + first-tile src only (scalars; af-prefetch would
// cost +32 regs -> 8-waves cliff).
// NOTE: no min-waves launch bound (r2/r3 lesson: forced budget -> 200 MB spills).
__global__ __launch_bounds__(512) void edge_conv(const _Float16* __restrict__ AB,
                                                 const _Float16* __restrict__ W2T_l,
                                                 const float* __restrict__ b2_l,
                                                 const int* __restrict__ rowptr,
                                                 const int* __restrict__ elist,
                                                 _Float16* __restrict__ hout, int n) {
    __shared__ _Float16 w2s[2048 * 8];   // 32 frags (kb*4+cb) x 64 lanes x 16B = 32 KB
    __shared__ float b2s[HID];
    int tid = threadIdx.x;
    #pragma unroll
    for (int i = 0; i < 4; i++) {
        int fid = i * 512 + tid;     // 0..2047
        int ln = fid & 63;
        int grp = fid >> 6;          // kb*4+cb
        int kb = grp >> 2;
        int cb = grp & 3;
        *(half8*)(w2s + (size_t)fid * 8) =
            load_h8(W2T_l + (size_t)(cb * 32 + (ln & 31)) * HID + kb * 16 + (ln >> 5) * 8);
    }
    if (tid < HID) b2s[tid] = b2_l[tid];
    __syncthreads();

    int lane = tid & 63;
    int er = lane & 31;     // edge-row within tile / output col within cb block
    int hi = lane >> 5;     // k-half
    int gw = (blockIdx.x * blockDim.x + tid) >> 6;
    int nw = (gridDim.x * blockDim.x) >> 6;
    if (gw >= n) return;

    // ---- pipeline prologue ----
    int v = gw;
    int rbeg0 = rowptr[v];
    int deg0 = rowptr[v + 1] - rbeg0;
    int src0 = (er < deg0) ? elist[rbeg0 + er] : v;
    int v1 = v + nw;
    int rbeg1 = 0, deg1 = 0;
    if (v1 < n) { rbeg1 = rowptr[v1]; deg1 = rowptr[v1 + 1] - rbeg1; }

    while (true) {
        int vn = v + nw;
        int vn2 = vn + nw;
        int rbeg2 = 0, deg2 = 0;
        if (vn2 < n) { rbeg2 = rowptr[vn2]; deg2 = rowptr[vn2 + 1] - rbeg2; }
        int src1 = (er < deg1) ? elist[rbeg1 + er] : vn;

        // A-half slices of node v: k = kb*16 + hi*8 + j
        const _Float16* ap = AB + (size_t)v * 256 + hi * 8;
        half8 af[8];
        #pragma unroll
        for (int kb = 0; kb < 8; kb++) af[kb] = load_h8(ap + kb * 16);

        int ntile = (deg0 + 32) >> 5;        // ceil((deg0+1)/32), pad = self-loop
        float macc[4];
        #pragma unroll
        for (int cb = 0; cb < 4; cb++) macc[cb] = -3.0e38f;

        int src = src0;
        for (int tI = 0; tI < ntile; tI++) {
            // gather B-half slices of this lane's edge
            const _Float16* bp = AB + (size_t)src * 256 + 128 + hi * 8;
            half8 s[8];
            #pragma unroll
            for (int kb = 0; kb < 8; kb++) s[kb] = load_h8(bp + kb * 16);

            // prefetch next tile's src (overlaps with compute)
            int en = (tI + 1) * 32 + er;
            int srcn = (tI + 1 < ntile && en < deg0) ? elist[rbeg0 + en] : v;

            // s = relu(af + s)
            #pragma unroll
            for (int kb = 0; kb < 8; kb++) {
                half8 t = af[kb] + s[kb];
                #pragma unroll
                for (int e2 = 0; e2 < 8; e2++) t[e2] = (t[e2] > (_Float16)0) ? t[e2] : (_Float16)0;
                s[kb] = t;
            }

            #pragma unroll
            for (int cb = 0; cb < 4; cb++) {
                f32x16 d;
                #pragma unroll
                for (int e2 = 0; e2 < 16; e2++) d[e2] = 0.f;
                #pragma unroll
                for (int kb = 0; kb < 8; kb++) {
                    half8 w = *(const half8*)(w2s + ((size_t)((kb * 4 + cb) * 64 + lane)) * 8);
                    d = __builtin_amdgcn_mfma_f32_32x32x16_f16(s[kb], w, d, 0, 0, 0);
                }
                // tree-max the 16 row values (row mapping irrelevant for max)
                float m0 = fmaxf(fmaxf(d[0], d[1]), fmaxf(d[2], d[3]));
                float m1 = fmaxf(fmaxf(d[4], d[5]), fmaxf(d[6], d[7]));
                float m2 = fmaxf(fmaxf(d[8], d[9]), fmaxf(d[10], d[11]));
                float m3 = fmaxf(fmaxf(d[12], d[13]), fmaxf(d[14], d[15]));
                macc[cb] = fmaxf(macc[cb], fmaxf(fmaxf(m0, m1), fmaxf(m2, m3)));
            }
            src = srcn;
        }

        // merge k-half partners (other 16 rows) and write
        #pragma unroll
        for (int cb = 0; cb < 4; cb++) {
            float m = fmaxf(macc[cb], __shfl_xor(macc[cb], 32));
            m += b2s[cb * 32 + er];
            if (lane < 32) hout[(size_t)v * HID + cb * 32 + er] = (_Float16)m;
        }

        // ---- rotate pipeline ----
        v = vn;
        if (v >= n) break;
        src0 = src1;
        rbeg0 = rbeg1; deg0 = deg1;
        rbeg1 = rbeg2; deg1 = deg2;
    }
}

// ---------------- decoder FC: out = h @ dW + db  (fp32 out [N][16]) ----------------
__global__ void fc_dec(const _Float16* __restrict__ h16, const float* __restrict__ W,
                       const float* __restrict__ b, float* __restrict__ out, int n) {
    __shared__ float row[HID];
    __shared__ float part[64];
    int node = blockIdx.x;
    if (node >= n) return;
    int t = threadIdx.x;
    row[t] = (float)h16[(size_t)node * HID + t];
    row[64 + t] = (float)h16[(size_t)node * HID + 64 + t];
    __syncthreads();
    int j = t & 15;
    int ks = t >> 4;   // 0..3, each covers 32 k
    float p = 0.f;
    for (int k = ks * 32; k < ks * 32 + 32; k++) p += row[k] * W[k * NDIM + j];
    part[t] = p;
    __syncthreads();
    if (t < 16) {
        float o = b[j] + part[j] + part[16 + j] + part[32 + j] + part[48 + j];
        out[(size_t)node * NDIM + j] = o;
    }
}

// ---------------- host ----------------
extern "C" void kernel_launch(void* const* d_in, const int* in_sizes, int n_in,
                              void* d_out, int out_size, void* d_ws, size_t ws_size,
                              hipStream_t stream) {
    const float* x   = (const float*)d_in[0];
    const int*   ei  = (const int*)d_in[1];
    const float* t   = (const float*)d_in[2];
    const float* neW = (const float*)d_in[3];
    const float* neb = (const float*)d_in[4];
    const float* cW1 = (const float*)d_in[5];
    const float* cb1 = (const float*)d_in[6];
    const float* cW2 = (const float*)d_in[7];
    const float* cb2 = (const float*)d_in[8];
    const float* eW  = (const float*)d_in[9];
    const float* eb  = (const float*)d_in[10];
    const float* dW  = (const float*)d_in[11];
    const float* db  = (const float*)d_in[12];
    const float* tpW = (const float*)d_in[13];
    const float* tpb = (const float*)d_in[14];

    int N = in_sizes[0] / NDIM;
    int E = in_sizes[1] / 2;

    char* w = (char*)d_ws;
    auto alloc = [&](size_t bytes) {
        void* p = (void*)w;
        w += (bytes + 255) & ~(size_t)255;
        return p;
    };
    float*     temb   = (float*)alloc(64 * 4);
    _Float16*  hA     = (_Float16*)alloc((size_t)N * HID * 2);
    _Float16*  hB     = (_Float16*)alloc((size_t)N * HID * 2);
    _Float16*  AB     = (_Float16*)alloc((size_t)N * 2 * HID * 2);
    _Float16*  WABT   = (_Float16*)alloc((size_t)NCONV * 2 * HID * HID * 2);
    _Float16*  W2T    = (_Float16*)alloc((size_t)NCONV * HID * HID * 2);
    _Float16*  encT   = (_Float16*)alloc((size_t)HID * HID * 2);
    int*       deg    = (int*)alloc((size_t)N * 4);
    int*       rowptr = (int*)alloc((size_t)(N + 1) * 4);
    int*       cursor = (int*)alloc((size_t)N * 4);
    int*       elist  = (int*)alloc((size_t)E * 4);

    // weights + time embedding + node embedding
    int prep_total = NCONV * HID * HID + HID * HID;
    prep_weights<<<(prep_total + 255) / 256, 256, 0, stream>>>(cW1, cW2, eW, WABT, W2T, encT);
    time_emb_kernel<<<1, 64, 0, stream>>>(t, tpW, tpb, temb);
    node_emb_kernel<<<N, HID, 0, stream>>>(x, temb, neW, neb, hA, N);

    // CSR by dst
    hipMemsetAsync(deg, 0, (size_t)N * 4, stream);
    count_deg<<<(E + 255) / 256, 256, 0, stream>>>(ei, deg, E);
    scan_csr<<<1, 1024, 0, stream>>>(deg, rowptr, cursor, N);
    fill_csr<<<(E + 255) / 256, 256, 0, stream>>>(ei, cursor, elist, E);

    int nmt = (N + 15) / 16;
    int ab_blocks = (nmt * 8 + 3) / 4;      // OUT=256 -> JW=8
    int fc_blocks = (nmt * 4 + 3) / 4;      // OUT=128 -> JW=4
    int ec_blocks = 512;                    // 512 thr/block: 2 blocks/CU, 16 waves/CU

    _Float16* cur = hA;
    for (int l = 0; l < NCONV; l++) {
        if (l == 4) {
            gemm_h<128><<<fc_blocks, 256, 0, stream>>>(cur, encT, eb, hB, N);
            cur = hB;
        }
        gemm_h<256><<<ab_blocks, 256, 0, stream>>>(cur, WABT + (size_t)l * 2 * HID * HID,
                                                   cb1 + (size_t)l * HID, AB, N);
        edge_conv<<<ec_blocks, 512, 0, stream>>>(AB, W2T + (size_t)l * HID * HID,
                                                 cb2 + (size_t)l * HID, rowptr, elist, cur, N);
    }

    fc_dec<<<N, HID, 0, stream>>>(cur, dW, db, (float*)d_out, N);
}